// Round 16
// baseline (3015.018 us; speedup 1.0000x reference)
//
#include <hip/hip_runtime.h>
#include <hip/hip_bf16.h>
#include <math.h>

// ---- problem constants ----
#define NL 26
#define TT 16
#define DD 768
#define HDD 128
#define FFF 3072
#define VV 32000
#define SCCH 4096
#define STOT 4112      // SC + T
#define OQKV 1536      // NG*(G+2)*HD
#define EPSF 1e-6f
#define SCALEQ 0.08838834764831845f  // 1/sqrt(128)
#define NCH 65         // 64 cache chunks of 64 + 1 new-token chunk

// ---------- helpers ----------
__device__ __forceinline__ float d4(const float4 a, const float4 b) {
    return fmaf(a.x, b.x, fmaf(a.y, b.y, fmaf(a.z, b.z, a.w * b.w)));
}
__device__ __forceinline__ float4 fma4(float p, const float4 v, float4 a) {
    return make_float4(fmaf(p, v.x, a.x), fmaf(p, v.y, a.y),
                       fmaf(p, v.z, a.z), fmaf(p, v.w, a.w));
}
__device__ __forceinline__ float4 f4add4(float4 a, float4 b, float4 c, float4 d) {
    return make_float4((a.x + b.x) + (c.x + d.x), (a.y + b.y) + (c.y + d.y),
                       (a.z + b.z) + (c.z + d.z), (a.w + b.w) + (c.w + d.w));
}
// h + f*s*(1+w)
__device__ __forceinline__ float4 f4res(float4 h, float4 f, float s, float4 w) {
    return make_float4(fmaf(f.x * s, 1.f + w.x, h.x), fmaf(f.y * s, 1.f + w.y, h.y),
                       fmaf(f.z * s, 1.f + w.z, h.z), fmaf(f.w * s, 1.f + w.w, h.w));
}
// h*s*(1+w)
__device__ __forceinline__ float4 f4nrm(float4 h, float s, float4 w) {
    return make_float4(h.x * s * (1.f + w.x), h.y * s * (1.f + w.y),
                       h.z * s * (1.f + w.z), h.w * s * (1.f + w.w));
}
__device__ __forceinline__ float r16(float v) {
    v += __shfl_xor(v, 1); v += __shfl_xor(v, 2); v += __shfl_xor(v, 4); v += __shfl_xor(v, 8);
    return v;
}
__device__ __forceinline__ float rwave(float v) {
    v += __shfl_xor(v, 32); v += __shfl_xor(v, 16); v += __shfl_xor(v, 8);
    v += __shfl_xor(v, 4);  v += __shfl_xor(v, 2);  v += __shfl_xor(v, 1);
    return v;
}
// fast tanh: saturation-safe rational form (rel err ~1e-7)
__device__ __forceinline__ float ftanh(float x) {
    float t = __expf(-2.f * fabsf(x));
    float th = (1.f - t) / (1.f + t);
    return copysignf(th, x);
}

// GEMV inner, 2 rows interleaved.
template <int K4>
__device__ __forceinline__ void gemv_row2(const float4* __restrict__ wa,
                                          const float4* __restrict__ wb,
                                          const float* __restrict__ xs, int lane,
                                          float* __restrict__ acca,
                                          float* __restrict__ accb) {
#pragma unroll
    for (int t = 0; t < TT; t++) { acca[t] = 0.f; accb[t] = 0.f; }
    const float4* x4 = reinterpret_cast<const float4*>(xs);
#pragma unroll
    for (int it = 0; it < K4 / 64; ++it) {
        float4 a = wa[it * 64 + lane];
        float4 b = wb[it * 64 + lane];
#pragma unroll
        for (int t = 0; t < TT; t++) {
            float4 x = x4[t * K4 + it * 64 + lane];
            acca[t] = fmaf(a.x, x.x, fmaf(a.y, x.y, fmaf(a.z, x.z, fmaf(a.w, x.w, acca[t]))));
            accb[t] = fmaf(b.x, x.x, fmaf(b.y, x.y, fmaf(b.z, x.z, fmaf(b.w, x.w, accb[t]))));
        }
    }
#pragma unroll
    for (int t = 0; t < TT; t++) { acca[t] = rwave(acca[t]); accb[t] = rwave(accb[t]); }
}

// GEMV inner, 3 rows interleaved.
template <int K4>
__device__ __forceinline__ void gemv_row3(const float4* __restrict__ wa,
                                          const float4* __restrict__ wb,
                                          const float4* __restrict__ wc,
                                          const float* __restrict__ xs, int lane,
                                          float* __restrict__ acca,
                                          float* __restrict__ accb,
                                          float* __restrict__ accc) {
#pragma unroll
    for (int t = 0; t < TT; t++) { acca[t] = 0.f; accb[t] = 0.f; accc[t] = 0.f; }
    const float4* x4 = reinterpret_cast<const float4*>(xs);
#pragma unroll
    for (int it = 0; it < K4 / 64; ++it) {
        float4 a = wa[it * 64 + lane];
        float4 b = wb[it * 64 + lane];
        float4 c = wc[it * 64 + lane];
#pragma unroll
        for (int t = 0; t < TT; t++) {
            float4 x = x4[t * K4 + it * 64 + lane];
            acca[t] = fmaf(a.x, x.x, fmaf(a.y, x.y, fmaf(a.z, x.z, fmaf(a.w, x.w, acca[t]))));
            accb[t] = fmaf(b.x, x.x, fmaf(b.y, x.y, fmaf(b.z, x.z, fmaf(b.w, x.w, accb[t]))));
            accc[t] = fmaf(c.x, x.x, fmaf(c.y, x.y, fmaf(c.z, x.z, fmaf(c.w, x.w, accc[t]))));
        }
    }
#pragma unroll
    for (int t = 0; t < TT; t++) {
        acca[t] = rwave(acca[t]); accb[t] = rwave(accb[t]); accc[t] = rwave(accc[t]);
    }
}

// GEMV inner, 4 rows interleaved (one shared x pass).
template <int K4>
__device__ __forceinline__ void gemv_row4(const float4* __restrict__ wa,
                                          const float4* __restrict__ wb,
                                          const float4* __restrict__ wc,
                                          const float4* __restrict__ wd,
                                          const float* __restrict__ xs, int lane,
                                          float* __restrict__ acca, float* __restrict__ accb,
                                          float* __restrict__ accc, float* __restrict__ accd) {
#pragma unroll
    for (int t = 0; t < TT; t++) { acca[t] = 0.f; accb[t] = 0.f; accc[t] = 0.f; accd[t] = 0.f; }
    const float4* x4 = reinterpret_cast<const float4*>(xs);
#pragma unroll
    for (int it = 0; it < K4 / 64; ++it) {
        float4 a = wa[it * 64 + lane];
        float4 b = wb[it * 64 + lane];
        float4 c = wc[it * 64 + lane];
        float4 d = wd[it * 64 + lane];
#pragma unroll
        for (int t = 0; t < TT; t++) {
            float4 x = x4[t * K4 + it * 64 + lane];
            acca[t] = fmaf(a.x, x.x, fmaf(a.y, x.y, fmaf(a.z, x.z, fmaf(a.w, x.w, acca[t]))));
            accb[t] = fmaf(b.x, x.x, fmaf(b.y, x.y, fmaf(b.z, x.z, fmaf(b.w, x.w, accb[t]))));
            accc[t] = fmaf(c.x, x.x, fmaf(c.y, x.y, fmaf(c.z, x.z, fmaf(c.w, x.w, accc[t]))));
            accd[t] = fmaf(d.x, x.x, fmaf(d.y, x.y, fmaf(d.z, x.z, fmaf(d.w, x.w, accd[t]))));
        }
    }
#pragma unroll
    for (int t = 0; t < TT; t++) {
        acca[t] = rwave(acca[t]); accb[t] = rwave(accb[t]);
        accc[t] = rwave(accc[t]); accd[t] = rwave(accd[t]);
    }
}

// GEMV inner, 6 rows interleaved (one shared x pass). Named accumulators only.
template <int K4>
__device__ __forceinline__ void gemv_row6(const float4* __restrict__ wa,
                                          const float4* __restrict__ wb,
                                          const float4* __restrict__ wc,
                                          const float4* __restrict__ wd,
                                          const float4* __restrict__ we,
                                          const float4* __restrict__ wf,
                                          const float* __restrict__ xs, int lane,
                                          float* __restrict__ acca, float* __restrict__ accb,
                                          float* __restrict__ accc, float* __restrict__ accd,
                                          float* __restrict__ acce, float* __restrict__ accf) {
#pragma unroll
    for (int t = 0; t < TT; t++) {
        acca[t] = 0.f; accb[t] = 0.f; accc[t] = 0.f;
        accd[t] = 0.f; acce[t] = 0.f; accf[t] = 0.f;
    }
    const float4* x4 = reinterpret_cast<const float4*>(xs);
#pragma unroll
    for (int it = 0; it < K4 / 64; ++it) {
        float4 a = wa[it * 64 + lane];
        float4 b = wb[it * 64 + lane];
        float4 c = wc[it * 64 + lane];
        float4 d = wd[it * 64 + lane];
        float4 e = we[it * 64 + lane];
        float4 f = wf[it * 64 + lane];
#pragma unroll
        for (int t = 0; t < TT; t++) {
            float4 x = x4[t * K4 + it * 64 + lane];
            acca[t] = fmaf(a.x, x.x, fmaf(a.y, x.y, fmaf(a.z, x.z, fmaf(a.w, x.w, acca[t]))));
            accb[t] = fmaf(b.x, x.x, fmaf(b.y, x.y, fmaf(b.z, x.z, fmaf(b.w, x.w, accb[t]))));
            accc[t] = fmaf(c.x, x.x, fmaf(c.y, x.y, fmaf(c.z, x.z, fmaf(c.w, x.w, accc[t]))));
            accd[t] = fmaf(d.x, x.x, fmaf(d.y, x.y, fmaf(d.z, x.z, fmaf(d.w, x.w, accd[t]))));
            acce[t] = fmaf(e.x, x.x, fmaf(e.y, x.y, fmaf(e.z, x.z, fmaf(e.w, x.w, acce[t]))));
            accf[t] = fmaf(f.x, x.x, fmaf(f.y, x.y, fmaf(f.z, x.z, fmaf(f.w, x.w, accf[t]))));
        }
    }
#pragma unroll
    for (int t = 0; t < TT; t++) {
        acca[t] = rwave(acca[t]); accb[t] = rwave(accb[t]); accc[t] = rwave(accc[t]);
        accd[t] = rwave(accd[t]); acce[t] = rwave(acce[t]); accf[t] = rwave(accf[t]);
    }
}

// ---------- K1: (deferred ff residual) + pre-attn rmsnorm + QKV GEMV ----------
// grid 192, 8 rows/block: wave wv owns pair (blk*8+wv, blk*8+wv+4).
__global__ __launch_bounds__(256) void k_qkv(const int first,
                                             const float* __restrict__ hB,
                                             const float* __restrict__ ff,   // [4][16][768]
                                             const float* __restrict__ emb,
                                             const float* __restrict__ pofn_prev,
                                             const float* __restrict__ pan,
                                             const float* __restrict__ W,    // [1536][768]
                                             float* __restrict__ qkvo,       // [16][1536]
                                             float* __restrict__ hA) {
    __shared__ __align__(16) float xs[TT * DD];
    const int tid = threadIdx.x;
    const int row = tid >> 4, c16 = tid & 15;
    float4* xr = reinterpret_cast<float4*>(xs) + row * 192;
    float4* hA4 = reinterpret_cast<float4*>(hA) + row * 192;
    if (first) {
        const float4* e4 = reinterpret_cast<const float4*>(emb) + row * 192;
        float ss = 0.f;
#pragma unroll
        for (int k = 0; k < 12; k++) { int i = c16 + 16 * k; float4 v = e4[i]; xr[i] = v; ss += d4(v, v); }
        ss = r16(ss);
        float inv = rsqrtf(ss * (1.f / 768.f) + EPSF);
        if (blockIdx.x == 0) {
#pragma unroll
            for (int k = 0; k < 12; k++) { int i = c16 + 16 * k; hA4[i] = xr[i]; }
        }
        const float4* p4 = reinterpret_cast<const float4*>(pan);
#pragma unroll
        for (int k = 0; k < 12; k++) { int i = c16 + 16 * k; xr[i] = f4nrm(xr[i], inv, p4[i]); }
    } else {
        const float4* f0 = reinterpret_cast<const float4*>(ff) + row * 192;
        const float4* f1 = f0 + TT * 192;
        const float4* f2 = f1 + TT * 192;
        const float4* f3 = f2 + TT * 192;
        float ss = 0.f;
#pragma unroll
        for (int k = 0; k < 12; k++) {
            int i = c16 + 16 * k;
            float4 v = f4add4(f0[i], f1[i], f2[i], f3[i]);
            xr[i] = v; ss += d4(v, v);
        }
        ss = r16(ss);
        float inv = rsqrtf(ss * (1.f / 768.f) + EPSF);
        const float4* hb4 = reinterpret_cast<const float4*>(hB) + row * 192;
        const float4* po4 = reinterpret_cast<const float4*>(pofn_prev);
        float ss2 = 0.f;
#pragma unroll
        for (int k = 0; k < 12; k++) {
            int i = c16 + 16 * k;
            float4 v = f4res(hb4[i], xr[i], inv, po4[i]);
            xr[i] = v; ss2 += d4(v, v);
            if (blockIdx.x == 0) hA4[i] = v;
        }
        ss2 = r16(ss2);
        float inv2 = rsqrtf(ss2 * (1.f / 768.f) + EPSF);
        const float4* p4 = reinterpret_cast<const float4*>(pan);
#pragma unroll
        for (int k = 0; k < 12; k++) { int i = c16 + 16 * k; xr[i] = f4nrm(xr[i], inv2, p4[i]); }
    }
    __syncthreads();
    const int wv = tid >> 6, lane = tid & 63;
    const int o0 = blockIdx.x * 8 + wv;
    const int o1 = o0 + 4;
    float acca[TT], accb[TT];
    gemv_row2<192>(reinterpret_cast<const float4*>(W + (size_t)o0 * DD),
                   reinterpret_cast<const float4*>(W + (size_t)o1 * DD), xs, lane, acca, accb);
    if (lane < TT) {
        qkvo[lane * OQKV + o0] = acca[lane];
        qkvo[lane * OQKV + o1] = accb[lane];
    }
}

// ---------- K2: attention partials, 16 q-rows per block (R15, unchanged) ----------
__global__ __launch_bounds__(256) void k_attn(const float* __restrict__ qkv,
                                              const float* __restrict__ kc,  // [2][4096][128]
                                              const float* __restrict__ vc,  // [2][128][4096]
                                              const float* __restrict__ cosp,
                                              const float* __restrict__ sinp,
                                              const float* __restrict__ mask, // [16][4112]
                                              const float* __restrict__ qnw,
                                              const float* __restrict__ knw,
                                              float* __restrict__ part,
                                              float* __restrict__ kout,   // [2][16][128]
                                              float* __restrict__ vout)   // [2][128][16]
{
    __shared__ __align__(16) float kvb[64 * 132];
    __shared__ __align__(16) float pls[16 * 68];
    const int tid = threadIdx.x;
    const int c = blockIdx.x;
    const int ng = blockIdx.y;
    const int rq = blockIdx.z;
    const bool newc = (c == 64);

    // --- Q build into kvb rows 0..15
    {
        int rl = tid >> 4, c16 = tid & 15;
        int r = rq * 16 + rl;
        int tsrc = r >> 2, g = r & 3;
        const float* src = qkv + tsrc * OQKV + ng * 768 + g * 128;
        float ss = 0.f;
#pragma unroll
        for (int j = 0; j < 8; j++) { float v = src[c16 * 8 + j]; ss += v * v; }
        ss = r16(ss);
        float inv = rsqrtf(ss * (1.f / 128.f) + EPSF);
        int pos = r & 15;
        const float* cp = cosp + pos * 128;
        const float* sp = sinp + pos * 128;
#pragma unroll
        for (int j = 0; j < 8; j++) {
            int d = c16 * 8 + j;
            float xn = src[d] * inv * (1.f + qnw[d]);
            float out;
            if (d < 64) { float pr = src[d + 64] * inv * (1.f + qnw[d + 64]); out = xn * cp[d] - pr * sp[d]; }
            else        { float pr = src[d - 64] * inv * (1.f + qnw[d - 64]); out = xn * cp[d] + pr * sp[d]; }
            kvb[rl * 132 + d] = out;
        }
    }
    const int rr = tid >> 4;
    const int half = (tid >> 3) & 1;
    const int dq = tid & 7;
    float4 qreg[4];
    {
        const float4* q4 = reinterpret_cast<const float4*>(kvb + rr * 132);
#pragma unroll
        for (int m = 0; m < 4; m++) qreg[m] = q4[dq + 8 * m];
    }
    __syncthreads();
    // --- K stage
    if (!newc) {
        int rowk = tid >> 2, q4i = tid & 3;
        const float4* k4 = reinterpret_cast<const float4*>(kc + (size_t)(ng * SCCH + c * 64 + rowk) * 128);
#pragma unroll
        for (int k = 0; k < 8; k++) {
            float4 v = k4[q4i * 8 + k];
            *reinterpret_cast<float4*>(&kvb[rowk * 132 + 4 * (q4i * 8 + k)]) = v;
        }
    } else {
        int t = tid >> 4, c16 = tid & 15;
        const float* src = qkv + t * OQKV + ng * 768 + 4 * 128;
        float ss = 0.f;
#pragma unroll
        for (int j = 0; j < 8; j++) { float v = src[c16 * 8 + j]; ss += v * v; }
        ss = r16(ss);
        float inv = rsqrtf(ss * (1.f / 128.f) + EPSF);
        const float* cp = cosp + t * 128;
        const float* sp = sinp + t * 128;
#pragma unroll
        for (int j = 0; j < 8; j++) {
            int d = c16 * 8 + j;
            float xn = src[d] * inv * (1.f + knw[d]);
            float out;
            if (d < 64) { float pr = src[d + 64] * inv * (1.f + knw[d + 64]); out = xn * cp[d] - pr * sp[d]; }
            else        { float pr = src[d - 64] * inv * (1.f + knw[d - 64]); out = xn * cp[d] + pr * sp[d]; }
            kvb[t * 132 + d] = out;
            if (rq == 0) kout[(ng * TT + t) * 128 + d] = out;
        }
        for (int i = tid; i < 48 * 132; i += 256) kvb[16 * 132 + i] = 0.f;
    }
    __syncthreads();
    // --- scores
    const int r = rq * 16 + rr;
    const int pos = r & 15;
    const int cnt_pos = newc ? TT : 64;
    const float* mrow = mask + pos * STOT + c * 64;
    float* prow = pls + rr * 68;
#pragma unroll 4
    for (int jj = 0; jj < 32; jj++) {
        int i = half * 32 + jj;
        const float4* krow = reinterpret_cast<const float4*>(kvb + i * 132);
        float p = d4(qreg[0], krow[dq]) + d4(qreg[1], krow[dq + 8])
                + d4(qreg[2], krow[dq + 16]) + d4(qreg[3], krow[dq + 24]);
        p += __shfl_xor(p, 1); p += __shfl_xor(p, 2); p += __shfl_xor(p, 4);
        if (i < cnt_pos) {
            p *= SCALEQ;
            p = 50.f * ftanh(p * 0.02f);
            p += mrow[i];
        } else {
            p = -1e30f;
        }
        prow[i] = p;
    }
    {
        const float4* prow4 = reinterpret_cast<const float4*>(prow);
        float m = -1e30f;
#pragma unroll 4
        for (int w = 0; w < 16; w++) {
            float4 v = prow4[w];
            m = fmaxf(m, fmaxf(fmaxf(v.x, v.y), fmaxf(v.z, v.w)));
        }
        float lsum = 0.f;
#pragma unroll 4
        for (int w = 0; w < 16; w++) {
            float4 v = prow4[w];
            lsum += (__expf(v.x - m) + __expf(v.y - m)) + (__expf(v.z - m) + __expf(v.w - m));
        }
#pragma unroll 2
        for (int j = 0; j < 4; j++) {
            int i = half * 32 + 8 * j + dq;
            prow[i] = __expf(prow[i] - m);
        }
        if ((tid & 15) == 0) {
            float* pb = part + (size_t)((ng * NCH + c) * 64 + r) * 132;
            pb[128] = m; pb[129] = lsum;
        }
    }
    __syncthreads();
    // --- V stage
    if (!newc) {
        int d = tid >> 1, hv = tid & 1;
        const float4* v4 = reinterpret_cast<const float4*>(vc + (size_t)(ng * 128 + d) * SCCH + c * 64);
#pragma unroll
        for (int k = 0; k < 8; k++) {
            float4 v = v4[hv * 8 + k];
            int sl = hv * 32 + 4 * k;
            kvb[(sl + 0) * 132 + d] = v.x;
            kvb[(sl + 1) * 132 + d] = v.y;
            kvb[(sl + 2) * 132 + d] = v.z;
            kvb[(sl + 3) * 132 + d] = v.w;
        }
    } else {
        int t = tid >> 4, c16 = tid & 15;
        const float* src = qkv + t * OQKV + ng * 768 + 5 * 128;
#pragma unroll
        for (int j = 0; j < 8; j++) {
            int d = c16 * 8 + j;
            float v = src[d];
            kvb[t * 132 + d] = v;
            if (rq == 0) vout[(ng * 128 + d) * TT + t] = v;
        }
    }
    __syncthreads();
    // --- PV
    float4 accv[4];
#pragma unroll
    for (int m2 = 0; m2 < 4; m2++) accv[m2] = make_float4(0.f, 0.f, 0.f, 0.f);
#pragma unroll 4
    for (int jj = 0; jj < 32; jj++) {
        int i = half * 32 + jj;
        float p = prow[i];
        const float4* v4 = reinterpret_cast<const float4*>(kvb + i * 132);
        accv[0] = fma4(p, v4[dq], accv[0]);
        accv[1] = fma4(p, v4[dq + 8], accv[1]);
        accv[2] = fma4(p, v4[dq + 16], accv[2]);
        accv[3] = fma4(p, v4[dq + 24], accv[3]);
    }
#pragma unroll
    for (int m2 = 0; m2 < 4; m2++) {
        accv[m2].x += __shfl_xor(accv[m2].x, 8);
        accv[m2].y += __shfl_xor(accv[m2].y, 8);
        accv[m2].z += __shfl_xor(accv[m2].z, 8);
        accv[m2].w += __shfl_xor(accv[m2].w, 8);
    }
    if (half == 0) {
        float* pb = part + (size_t)((ng * NCH + c) * 64 + r) * 132;
        float4* pb4 = reinterpret_cast<float4*>(pb);
        pb4[dq] = accv[0]; pb4[dq + 8] = accv[1]; pb4[dq + 16] = accv[2]; pb4[dq + 24] = accv[3];
    }
}

// ---------- K3: combine partials -> attn [t][h*128+d] (unchanged) ----------
__global__ __launch_bounds__(128) void k_combine(const float* __restrict__ part,
                                                 float* __restrict__ attn) {
    __shared__ float marr[NCH], larr[NCH], warr[NCH];
    __shared__ __align__(16) float mrg[4][128];
    int blk = blockIdx.x;
    int ng = blk >> 6, r = blk & 63;
    int tid = threadIdx.x;
    const float* pb = part + (size_t)(ng * NCH * 64 + r) * 132;
    if (tid < NCH) {
        marr[tid] = pb[(size_t)tid * 64 * 132 + 128];
        larr[tid] = pb[(size_t)tid * 64 * 132 + 129];
    }
    __syncthreads();
    float M = -1e30f;
#pragma unroll 4
    for (int cc = 0; cc < NCH; cc++) M = fmaxf(M, marr[cc]);
    if (tid < NCH) warr[tid] = __expf(marr[tid] - M);
    __syncthreads();
    float Lsum = 0.f;
#pragma unroll 4
    for (int cc = 0; cc < NCH; cc++) Lsum = fmaf(larr[cc], warr[cc], Lsum);
    int q = tid >> 5, dd = tid & 31;
    float4 A4 = make_float4(0.f, 0.f, 0.f, 0.f);
    for (int cc = q; cc < NCH; cc += 4) {
        const float4* pa = reinterpret_cast<const float4*>(pb + (size_t)cc * 64 * 132);
        A4 = fma4(warr[cc], pa[dd], A4);
    }
    *reinterpret_cast<float4*>(&mrg[q][dd * 4]) = A4;
    __syncthreads();
    int d = tid;
    float A = (mrg[0][d] + mrg[1][d]) + (mrg[2][d] + mrg[3][d]);
    int h = ng * 4 + (r >> 4), pos = r & 15;
    attn[pos * 1024 + h * 128 + d] = A / Lsum;
}

// ---------- K4: out projection (pairwise) ----------
__global__ __launch_bounds__(256) void k_outproj(const float* __restrict__ W, // [768][1024]
                                                 const float* __restrict__ attn,
                                                 float* __restrict__ y) {
    int tid = threadIdx.x;
    int wv = tid >> 6, lane = tid & 63;
    int o0 = blockIdx.x * 8 + wv;
    int o1 = o0 + 4;
    float acca[TT], accb[TT];
    gemv_row2<256>(reinterpret_cast<const float4*>(W + (size_t)o0 * 1024),
                   reinterpret_cast<const float4*>(W + (size_t)o1 * 1024), attn, lane, acca, accb);
    if (lane < TT) {
        y[lane * DD + o0] = acca[lane];
        y[lane * DD + o1] = accb[lane];
    }
}

// ---------- K5: post-attn residual+norm, pre-ff norm, gate/up GEMV6 + GELU*up ----------
// grid 256 (balanced 1/CU), 12 f-rows/block: wave wv owns f = blk*12 + wv*3 + {0,1,2}.
__global__ __launch_bounds__(256) void k_gateup(const float* __restrict__ hA,
                                                const float* __restrict__ y,
                                                const float* __restrict__ postw,
                                                const float* __restrict__ pfn,
                                                const float* __restrict__ gw,
                                                const float* __restrict__ uw,
                                                float* __restrict__ act,
                                                float* __restrict__ hB) {
    __shared__ __align__(16) float xs[TT * DD];
    int tid = threadIdx.x;
    int row = tid >> 4, c16 = tid & 15;
    float4* xr = reinterpret_cast<float4*>(xs) + row * 192;
    const float4* y4 = reinterpret_cast<const float4*>(y) + row * 192;
    float ss = 0.f;
#pragma unroll
    for (int k = 0; k < 12; k++) { int i = c16 + 16 * k; float4 v = y4[i]; xr[i] = v; ss += d4(v, v); }
    ss = r16(ss);
    float inv = rsqrtf(ss * (1.f / 768.f) + EPSF);
    const float4* ha4 = reinterpret_cast<const float4*>(hA) + row * 192;
    const float4* pw4 = reinterpret_cast<const float4*>(postw);
    float4* hB4 = reinterpret_cast<float4*>(hB) + row * 192;
    float ss2 = 0.f;
#pragma unroll
    for (int k = 0; k < 12; k++) {
        int i = c16 + 16 * k;
        float4 v = f4res(ha4[i], xr[i], inv, pw4[i]);
        xr[i] = v; ss2 += d4(v, v);
        if (blockIdx.x == 0) hB4[i] = v;
    }
    ss2 = r16(ss2);
    float inv2 = rsqrtf(ss2 * (1.f / 768.f) + EPSF);
    const float4* pf4 = reinterpret_cast<const float4*>(pfn);
#pragma unroll
    for (int k = 0; k < 12; k++) { int i = c16 + 16 * k; xr[i] = f4nrm(xr[i], inv2, pf4[i]); }
    __syncthreads();
    int wv = tid >> 6, lane = tid & 63;
    int f0 = blockIdx.x * 12 + wv * 3;
    int f1 = f0 + 1;
    int f2 = f0 + 2;
    float ag0[TT], ag1[TT], ag2[TT], au0[TT], au1[TT], au2[TT];
    gemv_row6<192>(reinterpret_cast<const float4*>(gw + (size_t)f0 * DD),
                   reinterpret_cast<const float4*>(gw + (size_t)f1 * DD),
                   reinterpret_cast<const float4*>(gw + (size_t)f2 * DD),
                   reinterpret_cast<const float4*>(uw + (size_t)f0 * DD),
                   reinterpret_cast<const float4*>(uw + (size_t)f1 * DD),
                   reinterpret_cast<const float4*>(uw + (size_t)f2 * DD),
                   xs, lane, ag0, ag1, ag2, au0, au1, au2);
    if (lane < TT) {
        {
            float g = ag0[lane], u = au0[lane];
            float inner = 0.7978845608028654f * fmaf(0.044715f * g, g * g, g);
            act[lane * FFF + f0] = 0.5f * g * (1.f + ftanh(inner)) * u;
        }
        {
            float g = ag1[lane], u = au1[lane];
            float inner = 0.7978845608028654f * fmaf(0.044715f * g, g * g, g);
            act[lane * FFF + f1] = 0.5f * g * (1.f + ftanh(inner)) * u;
        }
        {
            float g = ag2[lane], u = au2[lane];
            float inner = 0.7978845608028654f * fmaf(0.044715f * g, g * g, g);
            act[lane * FFF + f2] = 0.5f * g * (1.f + ftanh(inner)) * u;
        }
    }
}

// ---------- K6: down GEMV in f-quarters -> ff partials [4][16][768] ----------
// grid 256 (balanced): fq = blk&3, dc = blk>>2 (0..63); wave owns o = dc*12 + wv*3 + {0,1,2}.
__global__ __launch_bounds__(256) void k_down(const float* __restrict__ W, // [768][3072]
                                              const float* __restrict__ act,
                                              float* __restrict__ ffp) {
    __shared__ __align__(16) float xs[TT * DD];
    int tid = threadIdx.x;
    int fq = blockIdx.x & 3, dc = blockIdx.x >> 2;
    {
        const float4* a4 = reinterpret_cast<const float4*>(act);
        float4* s4 = reinterpret_cast<float4*>(xs);
#pragma unroll
        for (int k = 0; k < 12; k++) {
            int i = tid + 256 * k;
            int t = i / 192, cq = i - t * 192;
            s4[i] = a4[t * 768 + fq * 192 + cq];
        }
    }
    __syncthreads();
    int wv = tid >> 6, lane = tid & 63;
    int o0 = dc * 12 + wv * 3;
    int o1 = o0 + 1;
    int o2 = o0 + 2;
    float acca[TT], accb[TT], accc[TT];
    gemv_row3<192>(reinterpret_cast<const float4*>(W + (size_t)o0 * FFF + fq * 768),
                   reinterpret_cast<const float4*>(W + (size_t)o1 * FFF + fq * 768),
                   reinterpret_cast<const float4*>(W + (size_t)o2 * FFF + fq * 768),
                   xs, lane, acca, accb, accc);
    if (lane < TT) {
        ffp[(fq * TT + lane) * DD + o0] = acca[lane];
        ffp[(fq * TT + lane) * DD + o1] = accb[lane];
        ffp[(fq * TT + lane) * DD + o2] = accc[lane];
    }
}

// ---------- lm_head with fused final-x (quad rows) ----------
// grid 500, 64 rows/block: 4 quads per wave.
__global__ __launch_bounds__(256) void k_lmfused(const float* __restrict__ hB,
                                                 const float* __restrict__ ff,    // [4][16][768]
                                                 const float* __restrict__ pofn25,
                                                 const float* __restrict__ fnw,
                                                 const float* __restrict__ W,     // [32000][768]
                                                 float* __restrict__ logits) {
    __shared__ __align__(16) float xs[TT * DD];
    int tid = threadIdx.x;
    int row = tid >> 4, c16 = tid & 15;
    float4* xr = reinterpret_cast<float4*>(xs) + row * 192;
    const float4* f0 = reinterpret_cast<const float4*>(ff) + row * 192;
    const float4* f1 = f0 + TT * 192;
    const float4* f2 = f1 + TT * 192;
    const float4* f3 = f2 + TT * 192;
    float ss = 0.f;
#pragma unroll
    for (int k = 0; k < 12; k++) {
        int i = c16 + 16 * k;
        float4 v = f4add4(f0[i], f1[i], f2[i], f3[i]);
        xr[i] = v; ss += d4(v, v);
    }
    ss = r16(ss);
    float inv = rsqrtf(ss * (1.f / 768.f) + EPSF);
    const float4* hb4 = reinterpret_cast<const float4*>(hB) + row * 192;
    const float4* po4 = reinterpret_cast<const float4*>(pofn25);
    float ss2 = 0.f;
#pragma unroll
    for (int k = 0; k < 12; k++) {
        int i = c16 + 16 * k;
        float4 v = f4res(hb4[i], xr[i], inv, po4[i]);
        xr[i] = v; ss2 += d4(v, v);
    }
    ss2 = r16(ss2);
    float inv2 = rsqrtf(ss2 * (1.f / 768.f) + EPSF);
    const float4* fn4 = reinterpret_cast<const float4*>(fnw);
#pragma unroll
    for (int k = 0; k < 12; k++) { int i = c16 + 16 * k; xr[i] = f4nrm(xr[i], inv2, fn4[i]); }
    __syncthreads();
    int wv = tid >> 6, lane = tid & 63;
#pragma unroll
    for (int rr = 0; rr < 4; ++rr) {
        int o0 = blockIdx.x * 64 + rr * 16 + wv;
        int o1 = o0 + 4;
        int o2 = o0 + 8;
        int o3 = o0 + 12;
        float acca[TT], accb[TT], accc[TT], accd[TT];
        gemv_row4<192>(reinterpret_cast<const float4*>(W + (size_t)o0 * DD),
                       reinterpret_cast<const float4*>(W + (size_t)o1 * DD),
                       reinterpret_cast<const float4*>(W + (size_t)o2 * DD),
                       reinterpret_cast<const float4*>(W + (size_t)o3 * DD),
                       xs, lane, acca, accb, accc, accd);
        if (lane < TT) {
            logits[lane * VV + o0] = acca[lane];
            logits[lane * VV + o1] = accb[lane];
            logits[lane * VV + o2] = accc[lane];
            logits[lane * VV + o3] = accd[lane];
        }
    }
}

extern "C" void kernel_launch(void* const* d_in, const int* in_sizes, int n_in,
                              void* d_out, int out_size, void* d_ws, size_t ws_size,
                              hipStream_t stream) {
    const float* emb   = (const float*)d_in[0];
    const float* maskg = (const float*)d_in[1];
    const float* maskl = (const float*)d_in[2];
    const float* cosg  = (const float*)d_in[3];
    const float* sing  = (const float*)d_in[4];
    const float* cosl  = (const float*)d_in[5];
    const float* sinl  = (const float*)d_in[6];
    const float* kck   = (const float*)d_in[7];
    const float* kcv   = (const float*)d_in[8];
    const float* pan   = (const float*)d_in[9];
    const float* qkvw  = (const float*)d_in[10];
    const float* qnw   = (const float*)d_in[11];
    const float* knw   = (const float*)d_in[12];
    const float* outw  = (const float*)d_in[13];
    const float* postw = (const float*)d_in[14];
    const float* pfnw  = (const float*)d_in[15];
    const float* gw    = (const float*)d_in[16];
    const float* uw    = (const float*)d_in[17];
    const float* dw    = (const float*)d_in[18];
    const float* pofn  = (const float*)d_in[19];
    const float* fnw   = (const float*)d_in[20];
    const float* lmw   = (const float*)d_in[21];

    float* ws   = (float*)d_ws;
    float* hA   = ws;                 // 12288
    float* hB   = hA + 12288;         // 12288
    float* qkvb = hB + 12288;         // 24576
    float* attnb = qkvb + 24576;      // 16384
    float* yb   = attnb + 16384;      // 12288
    float* act  = yb + 12288;         // 49152
    float* ffp  = act + 49152;        // 49152
    float* part = ffp + 49152;        // 2*65*64*132 = 1,098,240

    float* outp = (float*)d_out;
    float* outK = outp + 512000;
    float* outV = outK + 106496;

    for (int l = 0; l < NL; l++) {
        int loc = ((l + 1) % 6) == 0;
        const float* cosp = loc ? cosl : cosg;
        const float* sinp = loc ? sinl : sing;
        const float* maskp = loc ? maskl : maskg;
        k_qkv<<<192, 256, 0, stream>>>(l == 0 ? 1 : 0, hB, ffp, emb,
                                       l ? (pofn + (size_t)(l - 1) * DD) : pofn,
                                       pan + (size_t)l * DD,
                                       qkvw + (size_t)l * OQKV * DD, qkvb, hA);
        k_attn<<<dim3(NCH, 2, 4), 256, 0, stream>>>(qkvb,
                                                    kck + (size_t)l * 2 * SCCH * HDD,
                                                    kcv + (size_t)l * 2 * HDD * SCCH,
                                                    cosp, sinp, maskp,
                                                    qnw + (size_t)l * HDD, knw + (size_t)l * HDD,
                                                    part,
                                                    outK + (size_t)l * 2 * TT * HDD,
                                                    outV + (size_t)l * 2 * HDD * TT);
        k_combine<<<128, 128, 0, stream>>>(part, attnb);
        k_outproj<<<96, 256, 0, stream>>>(outw + (size_t)l * DD * 1024, attnb, yb);
        k_gateup<<<256, 256, 0, stream>>>(hA, yb, postw + (size_t)l * DD, pfnw + (size_t)l * DD,
                                          gw + (size_t)l * FFF * DD, uw + (size_t)l * FFF * DD,
                                          act, hB);
        k_down<<<256, 256, 0, stream>>>(dw + (size_t)l * DD * FFF, act, ffp);
    }
    k_lmfused<<<500, 256, 0, stream>>>(hB, ffp, pofn + (size_t)25 * DD, fnw, lmw, outp);
}

// Round 18
// 2756.693 us; speedup vs baseline: 1.0937x; 1.0937x over previous
//
#include <hip/hip_runtime.h>
#include <hip/hip_bf16.h>
#include <math.h>

// ---- problem constants ----
#define NL 26
#define TT 16
#define DD 768
#define HDD 128
#define FFF 3072
#define VV 32000
#define SCCH 4096
#define STOT 4112      // SC + T
#define OQKV 1536      // NG*(G+2)*HD
#define EPSF 1e-6f
#define SCALEQ 0.08838834764831845f  // 1/sqrt(128)
#define NCH 65         // 64 cache chunks of 64 + 1 new-token chunk

// native vector type for nontemporal builtins
typedef float nfloat4 __attribute__((ext_vector_type(4)));

// ---------- helpers ----------
__device__ __forceinline__ float d4(const float4 a, const float4 b) {
    return fmaf(a.x, b.x, fmaf(a.y, b.y, fmaf(a.z, b.z, a.w * b.w)));
}
__device__ __forceinline__ float4 fma4(float p, const float4 v, float4 a) {
    return make_float4(fmaf(p, v.x, a.x), fmaf(p, v.y, a.y),
                       fmaf(p, v.z, a.z), fmaf(p, v.w, a.w));
}
__device__ __forceinline__ float4 f4add4(float4 a, float4 b, float4 c, float4 d) {
    return make_float4((a.x + b.x) + (c.x + d.x), (a.y + b.y) + (c.y + d.y),
                       (a.z + b.z) + (c.z + d.z), (a.w + b.w) + (c.w + d.w));
}
// h + f*s*(1+w)
__device__ __forceinline__ float4 f4res(float4 h, float4 f, float s, float4 w) {
    return make_float4(fmaf(f.x * s, 1.f + w.x, h.x), fmaf(f.y * s, 1.f + w.y, h.y),
                       fmaf(f.z * s, 1.f + w.z, h.z), fmaf(f.w * s, 1.f + w.w, h.w));
}
// h*s*(1+w)
__device__ __forceinline__ float4 f4nrm(float4 h, float s, float4 w) {
    return make_float4(h.x * s * (1.f + w.x), h.y * s * (1.f + w.y),
                       h.z * s * (1.f + w.z), h.w * s * (1.f + w.w));
}
__device__ __forceinline__ float r16(float v) {
    v += __shfl_xor(v, 1); v += __shfl_xor(v, 2); v += __shfl_xor(v, 4); v += __shfl_xor(v, 8);
    return v;
}
__device__ __forceinline__ float rwave(float v) {
    v += __shfl_xor(v, 32); v += __shfl_xor(v, 16); v += __shfl_xor(v, 8);
    v += __shfl_xor(v, 4);  v += __shfl_xor(v, 2);  v += __shfl_xor(v, 1);
    return v;
}
// fast tanh: saturation-safe rational form (rel err ~1e-7)
__device__ __forceinline__ float ftanh(float x) {
    float t = __expf(-2.f * fabsf(x));
    float th = (1.f - t) / (1.f + t);
    return copysignf(th, x);
}
// non-temporal float4 load (weights are single-use streams; keep L2 for hot data)
__device__ __forceinline__ float4 ldnt4(const float4* __restrict__ p) {
    nfloat4 v = __builtin_nontemporal_load(reinterpret_cast<const nfloat4*>(p));
    return make_float4(v.x, v.y, v.z, v.w);
}

// GEMV inner, 2 rows interleaved (NT weight loads).
template <int K4>
__device__ __forceinline__ void gemv_row2(const float4* __restrict__ wa,
                                          const float4* __restrict__ wb,
                                          const float* __restrict__ xs, int lane,
                                          float* __restrict__ acca,
                                          float* __restrict__ accb) {
#pragma unroll
    for (int t = 0; t < TT; t++) { acca[t] = 0.f; accb[t] = 0.f; }
    const float4* x4 = reinterpret_cast<const float4*>(xs);
#pragma unroll
    for (int it = 0; it < K4 / 64; ++it) {
        float4 a = ldnt4(&wa[it * 64 + lane]);
        float4 b = ldnt4(&wb[it * 64 + lane]);
#pragma unroll
        for (int t = 0; t < TT; t++) {
            float4 x = x4[t * K4 + it * 64 + lane];
            acca[t] = fmaf(a.x, x.x, fmaf(a.y, x.y, fmaf(a.z, x.z, fmaf(a.w, x.w, acca[t]))));
            accb[t] = fmaf(b.x, x.x, fmaf(b.y, x.y, fmaf(b.z, x.z, fmaf(b.w, x.w, accb[t]))));
        }
    }
#pragma unroll
    for (int t = 0; t < TT; t++) { acca[t] = rwave(acca[t]); accb[t] = rwave(accb[t]); }
}

// GEMV inner, 4 rows interleaved (one shared x pass, NT weight loads).
template <int K4>
__device__ __forceinline__ void gemv_row4(const float4* __restrict__ wa,
                                          const float4* __restrict__ wb,
                                          const float4* __restrict__ wc,
                                          const float4* __restrict__ wd,
                                          const float* __restrict__ xs, int lane,
                                          float* __restrict__ acca, float* __restrict__ accb,
                                          float* __restrict__ accc, float* __restrict__ accd) {
#pragma unroll
    for (int t = 0; t < TT; t++) { acca[t] = 0.f; accb[t] = 0.f; accc[t] = 0.f; accd[t] = 0.f; }
    const float4* x4 = reinterpret_cast<const float4*>(xs);
#pragma unroll
    for (int it = 0; it < K4 / 64; ++it) {
        float4 a = ldnt4(&wa[it * 64 + lane]);
        float4 b = ldnt4(&wb[it * 64 + lane]);
        float4 c = ldnt4(&wc[it * 64 + lane]);
        float4 d = ldnt4(&wd[it * 64 + lane]);
#pragma unroll
        for (int t = 0; t < TT; t++) {
            float4 x = x4[t * K4 + it * 64 + lane];
            acca[t] = fmaf(a.x, x.x, fmaf(a.y, x.y, fmaf(a.z, x.z, fmaf(a.w, x.w, acca[t]))));
            accb[t] = fmaf(b.x, x.x, fmaf(b.y, x.y, fmaf(b.z, x.z, fmaf(b.w, x.w, accb[t]))));
            accc[t] = fmaf(c.x, x.x, fmaf(c.y, x.y, fmaf(c.z, x.z, fmaf(c.w, x.w, accc[t]))));
            accd[t] = fmaf(d.x, x.x, fmaf(d.y, x.y, fmaf(d.z, x.z, fmaf(d.w, x.w, accd[t]))));
        }
    }
#pragma unroll
    for (int t = 0; t < TT; t++) {
        acca[t] = rwave(acca[t]); accb[t] = rwave(accb[t]);
        accc[t] = rwave(accc[t]); accd[t] = rwave(accd[t]);
    }
}

// ---------- K1: (deferred ff residual) + pre-attn rmsnorm + QKV GEMV ----------
// grid 192, 8 rows/block: wave wv owns pair (blk*8+wv, blk*8+wv+4).
__global__ __launch_bounds__(256) void k_qkv(const int first,
                                             const float* __restrict__ hB,
                                             const float* __restrict__ ff,   // [4][16][768]
                                             const float* __restrict__ emb,
                                             const float* __restrict__ pofn_prev,
                                             const float* __restrict__ pan,
                                             const float* __restrict__ W,    // [1536][768]
                                             float* __restrict__ qkvo,       // [16][1536]
                                             float* __restrict__ hA) {
    __shared__ __align__(16) float xs[TT * DD];
    const int tid = threadIdx.x;
    const int row = tid >> 4, c16 = tid & 15;
    float4* xr = reinterpret_cast<float4*>(xs) + row * 192;
    float4* hA4 = reinterpret_cast<float4*>(hA) + row * 192;
    if (first) {
        const float4* e4 = reinterpret_cast<const float4*>(emb) + row * 192;
        float ss = 0.f;
#pragma unroll
        for (int k = 0; k < 12; k++) { int i = c16 + 16 * k; float4 v = e4[i]; xr[i] = v; ss += d4(v, v); }
        ss = r16(ss);
        float inv = rsqrtf(ss * (1.f / 768.f) + EPSF);
        if (blockIdx.x == 0) {
#pragma unroll
            for (int k = 0; k < 12; k++) { int i = c16 + 16 * k; hA4[i] = xr[i]; }
        }
        const float4* p4 = reinterpret_cast<const float4*>(pan);
#pragma unroll
        for (int k = 0; k < 12; k++) { int i = c16 + 16 * k; xr[i] = f4nrm(xr[i], inv, p4[i]); }
    } else {
        const float4* f0 = reinterpret_cast<const float4*>(ff) + row * 192;
        const float4* f1 = f0 + TT * 192;
        const float4* f2 = f1 + TT * 192;
        const float4* f3 = f2 + TT * 192;
        float ss = 0.f;
#pragma unroll
        for (int k = 0; k < 12; k++) {
            int i = c16 + 16 * k;
            float4 v = f4add4(f0[i], f1[i], f2[i], f3[i]);
            xr[i] = v; ss += d4(v, v);
        }
        ss = r16(ss);
        float inv = rsqrtf(ss * (1.f / 768.f) + EPSF);
        const float4* hb4 = reinterpret_cast<const float4*>(hB) + row * 192;
        const float4* po4 = reinterpret_cast<const float4*>(pofn_prev);
        float ss2 = 0.f;
#pragma unroll
        for (int k = 0; k < 12; k++) {
            int i = c16 + 16 * k;
            float4 v = f4res(hb4[i], xr[i], inv, po4[i]);
            xr[i] = v; ss2 += d4(v, v);
            if (blockIdx.x == 0) hA4[i] = v;
        }
        ss2 = r16(ss2);
        float inv2 = rsqrtf(ss2 * (1.f / 768.f) + EPSF);
        const float4* p4 = reinterpret_cast<const float4*>(pan);
#pragma unroll
        for (int k = 0; k < 12; k++) { int i = c16 + 16 * k; xr[i] = f4nrm(xr[i], inv2, p4[i]); }
    }
    __syncthreads();
    const int wv = tid >> 6, lane = tid & 63;
    const int o0 = blockIdx.x * 8 + wv;
    const int o1 = o0 + 4;
    float acca[TT], accb[TT];
    gemv_row2<192>(reinterpret_cast<const float4*>(W + (size_t)o0 * DD),
                   reinterpret_cast<const float4*>(W + (size_t)o1 * DD), xs, lane, acca, accb);
    if (lane < TT) {
        qkvo[lane * OQKV + o0] = acca[lane];
        qkvo[lane * OQKV + o1] = accb[lane];
    }
}

// ---------- K2: attention partials, 16 q-rows per block (R15, unchanged) ----------
__global__ __launch_bounds__(256) void k_attn(const float* __restrict__ qkv,
                                              const float* __restrict__ kc,  // [2][4096][128]
                                              const float* __restrict__ vc,  // [2][128][4096]
                                              const float* __restrict__ cosp,
                                              const float* __restrict__ sinp,
                                              const float* __restrict__ mask, // [16][4112]
                                              const float* __restrict__ qnw,
                                              const float* __restrict__ knw,
                                              float* __restrict__ part,
                                              float* __restrict__ kout,   // [2][16][128]
                                              float* __restrict__ vout)   // [2][128][16]
{
    __shared__ __align__(16) float kvb[64 * 132];
    __shared__ __align__(16) float pls[16 * 68];
    const int tid = threadIdx.x;
    const int c = blockIdx.x;
    const int ng = blockIdx.y;
    const int rq = blockIdx.z;
    const bool newc = (c == 64);

    // --- Q build into kvb rows 0..15
    {
        int rl = tid >> 4, c16 = tid & 15;
        int r = rq * 16 + rl;
        int tsrc = r >> 2, g = r & 3;
        const float* src = qkv + tsrc * OQKV + ng * 768 + g * 128;
        float ss = 0.f;
#pragma unroll
        for (int j = 0; j < 8; j++) { float v = src[c16 * 8 + j]; ss += v * v; }
        ss = r16(ss);
        float inv = rsqrtf(ss * (1.f / 128.f) + EPSF);
        int pos = r & 15;
        const float* cp = cosp + pos * 128;
        const float* sp = sinp + pos * 128;
#pragma unroll
        for (int j = 0; j < 8; j++) {
            int d = c16 * 8 + j;
            float xn = src[d] * inv * (1.f + qnw[d]);
            float out;
            if (d < 64) { float pr = src[d + 64] * inv * (1.f + qnw[d + 64]); out = xn * cp[d] - pr * sp[d]; }
            else        { float pr = src[d - 64] * inv * (1.f + qnw[d - 64]); out = xn * cp[d] + pr * sp[d]; }
            kvb[rl * 132 + d] = out;
        }
    }
    const int rr = tid >> 4;
    const int half = (tid >> 3) & 1;
    const int dq = tid & 7;
    float4 qreg[4];
    {
        const float4* q4 = reinterpret_cast<const float4*>(kvb + rr * 132);
#pragma unroll
        for (int m = 0; m < 4; m++) qreg[m] = q4[dq + 8 * m];
    }
    __syncthreads();
    // --- K stage
    if (!newc) {
        int rowk = tid >> 2, q4i = tid & 3;
        const float4* k4 = reinterpret_cast<const float4*>(kc + (size_t)(ng * SCCH + c * 64 + rowk) * 128);
#pragma unroll
        for (int k = 0; k < 8; k++) {
            float4 v = k4[q4i * 8 + k];
            *reinterpret_cast<float4*>(&kvb[rowk * 132 + 4 * (q4i * 8 + k)]) = v;
        }
    } else {
        int t = tid >> 4, c16 = tid & 15;
        const float* src = qkv + t * OQKV + ng * 768 + 4 * 128;
        float ss = 0.f;
#pragma unroll
        for (int j = 0; j < 8; j++) { float v = src[c16 * 8 + j]; ss += v * v; }
        ss = r16(ss);
        float inv = rsqrtf(ss * (1.f / 128.f) + EPSF);
        const float* cp = cosp + t * 128;
        const float* sp = sinp + t * 128;
#pragma unroll
        for (int j = 0; j < 8; j++) {
            int d = c16 * 8 + j;
            float xn = src[d] * inv * (1.f + knw[d]);
            float out;
            if (d < 64) { float pr = src[d + 64] * inv * (1.f + knw[d + 64]); out = xn * cp[d] - pr * sp[d]; }
            else        { float pr = src[d - 64] * inv * (1.f + knw[d - 64]); out = xn * cp[d] + pr * sp[d]; }
            kvb[t * 132 + d] = out;
            if (rq == 0) kout[(ng * TT + t) * 128 + d] = out;
        }
        for (int i = tid; i < 48 * 132; i += 256) kvb[16 * 132 + i] = 0.f;
    }
    __syncthreads();
    // --- scores
    const int r = rq * 16 + rr;
    const int pos = r & 15;
    const int cnt_pos = newc ? TT : 64;
    const float* mrow = mask + pos * STOT + c * 64;
    float* prow = pls + rr * 68;
#pragma unroll 4
    for (int jj = 0; jj < 32; jj++) {
        int i = half * 32 + jj;
        const float4* krow = reinterpret_cast<const float4*>(kvb + i * 132);
        float p = d4(qreg[0], krow[dq]) + d4(qreg[1], krow[dq + 8])
                + d4(qreg[2], krow[dq + 16]) + d4(qreg[3], krow[dq + 24]);
        p += __shfl_xor(p, 1); p += __shfl_xor(p, 2); p += __shfl_xor(p, 4);
        if (i < cnt_pos) {
            p *= SCALEQ;
            p = 50.f * ftanh(p * 0.02f);
            p += mrow[i];
        } else {
            p = -1e30f;
        }
        prow[i] = p;
    }
    {
        const float4* prow4 = reinterpret_cast<const float4*>(prow);
        float m = -1e30f;
#pragma unroll 4
        for (int w = 0; w < 16; w++) {
            float4 v = prow4[w];
            m = fmaxf(m, fmaxf(fmaxf(v.x, v.y), fmaxf(v.z, v.w)));
        }
        float lsum = 0.f;
#pragma unroll 4
        for (int w = 0; w < 16; w++) {
            float4 v = prow4[w];
            lsum += (__expf(v.x - m) + __expf(v.y - m)) + (__expf(v.z - m) + __expf(v.w - m));
        }
#pragma unroll 2
        for (int j = 0; j < 4; j++) {
            int i = half * 32 + 8 * j + dq;
            prow[i] = __expf(prow[i] - m);
        }
        if ((tid & 15) == 0) {
            float* pb = part + (size_t)((ng * NCH + c) * 64 + r) * 132;
            pb[128] = m; pb[129] = lsum;
        }
    }
    __syncthreads();
    // --- V stage
    if (!newc) {
        int d = tid >> 1, hv = tid & 1;
        const float4* v4 = reinterpret_cast<const float4*>(vc + (size_t)(ng * 128 + d) * SCCH + c * 64);
#pragma unroll
        for (int k = 0; k < 8; k++) {
            float4 v = v4[hv * 8 + k];
            int sl = hv * 32 + 4 * k;
            kvb[(sl + 0) * 132 + d] = v.x;
            kvb[(sl + 1) * 132 + d] = v.y;
            kvb[(sl + 2) * 132 + d] = v.z;
            kvb[(sl + 3) * 132 + d] = v.w;
        }
    } else {
        int t = tid >> 4, c16 = tid & 15;
        const float* src = qkv + t * OQKV + ng * 768 + 5 * 128;
#pragma unroll
        for (int j = 0; j < 8; j++) {
            int d = c16 * 8 + j;
            float v = src[d];
            kvb[t * 132 + d] = v;
            if (rq == 0) vout[(ng * 128 + d) * TT + t] = v;
        }
    }
    __syncthreads();
    // --- PV
    float4 accv[4];
#pragma unroll
    for (int m2 = 0; m2 < 4; m2++) accv[m2] = make_float4(0.f, 0.f, 0.f, 0.f);
#pragma unroll 4
    for (int jj = 0; jj < 32; jj++) {
        int i = half * 32 + jj;
        float p = prow[i];
        const float4* v4 = reinterpret_cast<const float4*>(kvb + i * 132);
        accv[0] = fma4(p, v4[dq], accv[0]);
        accv[1] = fma4(p, v4[dq + 8], accv[1]);
        accv[2] = fma4(p, v4[dq + 16], accv[2]);
        accv[3] = fma4(p, v4[dq + 24], accv[3]);
    }
#pragma unroll
    for (int m2 = 0; m2 < 4; m2++) {
        accv[m2].x += __shfl_xor(accv[m2].x, 8);
        accv[m2].y += __shfl_xor(accv[m2].y, 8);
        accv[m2].z += __shfl_xor(accv[m2].z, 8);
        accv[m2].w += __shfl_xor(accv[m2].w, 8);
    }
    if (half == 0) {
        float* pb = part + (size_t)((ng * NCH + c) * 64 + r) * 132;
        float4* pb4 = reinterpret_cast<float4*>(pb);
        pb4[dq] = accv[0]; pb4[dq + 8] = accv[1]; pb4[dq + 16] = accv[2]; pb4[dq + 24] = accv[3];
    }
}

// ---------- K3: combine partials -> attn [t][h*128+d] (unchanged) ----------
__global__ __launch_bounds__(128) void k_combine(const float* __restrict__ part,
                                                 float* __restrict__ attn) {
    __shared__ float marr[NCH], larr[NCH], warr[NCH];
    __shared__ __align__(16) float mrg[4][128];
    int blk = blockIdx.x;
    int ng = blk >> 6, r = blk & 63;
    int tid = threadIdx.x;
    const float* pb = part + (size_t)(ng * NCH * 64 + r) * 132;
    if (tid < NCH) {
        marr[tid] = pb[(size_t)tid * 64 * 132 + 128];
        larr[tid] = pb[(size_t)tid * 64 * 132 + 129];
    }
    __syncthreads();
    float M = -1e30f;
#pragma unroll 4
    for (int cc = 0; cc < NCH; cc++) M = fmaxf(M, marr[cc]);
    if (tid < NCH) warr[tid] = __expf(marr[tid] - M);
    __syncthreads();
    float Lsum = 0.f;
#pragma unroll 4
    for (int cc = 0; cc < NCH; cc++) Lsum = fmaf(larr[cc], warr[cc], Lsum);
    int q = tid >> 5, dd = tid & 31;
    float4 A4 = make_float4(0.f, 0.f, 0.f, 0.f);
    for (int cc = q; cc < NCH; cc += 4) {
        const float4* pa = reinterpret_cast<const float4*>(pb + (size_t)cc * 64 * 132);
        A4 = fma4(warr[cc], pa[dd], A4);
    }
    *reinterpret_cast<float4*>(&mrg[q][dd * 4]) = A4;
    __syncthreads();
    int d = tid;
    float A = (mrg[0][d] + mrg[1][d]) + (mrg[2][d] + mrg[3][d]);
    int h = ng * 4 + (r >> 4), pos = r & 15;
    attn[pos * 1024 + h * 128 + d] = A / Lsum;
}

// ---------- K4: out projection (pairwise) ----------
__global__ __launch_bounds__(256) void k_outproj(const float* __restrict__ W, // [768][1024]
                                                 const float* __restrict__ attn,
                                                 float* __restrict__ y) {
    int tid = threadIdx.x;
    int wv = tid >> 6, lane = tid & 63;
    int o0 = blockIdx.x * 8 + wv;
    int o1 = o0 + 4;
    float acca[TT], accb[TT];
    gemv_row2<256>(reinterpret_cast<const float4*>(W + (size_t)o0 * 1024),
                   reinterpret_cast<const float4*>(W + (size_t)o1 * 1024), attn, lane, acca, accb);
    if (lane < TT) {
        y[lane * DD + o0] = acca[lane];
        y[lane * DD + o1] = accb[lane];
    }
}

// ---------- K5: post-attn residual+norm, pre-ff norm, gate/up GEMV4 + GELU*up ----------
// grid 384, 8 f-rows/block (R15 config).
__global__ __launch_bounds__(256) void k_gateup(const float* __restrict__ hA,
                                                const float* __restrict__ y,
                                                const float* __restrict__ postw,
                                                const float* __restrict__ pfn,
                                                const float* __restrict__ gw,
                                                const float* __restrict__ uw,
                                                float* __restrict__ act,
                                                float* __restrict__ hB) {
    __shared__ __align__(16) float xs[TT * DD];
    int tid = threadIdx.x;
    int row = tid >> 4, c16 = tid & 15;
    float4* xr = reinterpret_cast<float4*>(xs) + row * 192;
    const float4* y4 = reinterpret_cast<const float4*>(y) + row * 192;
    float ss = 0.f;
#pragma unroll
    for (int k = 0; k < 12; k++) { int i = c16 + 16 * k; float4 v = y4[i]; xr[i] = v; ss += d4(v, v); }
    ss = r16(ss);
    float inv = rsqrtf(ss * (1.f / 768.f) + EPSF);
    const float4* ha4 = reinterpret_cast<const float4*>(hA) + row * 192;
    const float4* pw4 = reinterpret_cast<const float4*>(postw);
    float4* hB4 = reinterpret_cast<float4*>(hB) + row * 192;
    float ss2 = 0.f;
#pragma unroll
    for (int k = 0; k < 12; k++) {
        int i = c16 + 16 * k;
        float4 v = f4res(ha4[i], xr[i], inv, pw4[i]);
        xr[i] = v; ss2 += d4(v, v);
        if (blockIdx.x == 0) hB4[i] = v;
    }
    ss2 = r16(ss2);
    float inv2 = rsqrtf(ss2 * (1.f / 768.f) + EPSF);
    const float4* pf4 = reinterpret_cast<const float4*>(pfn);
#pragma unroll
    for (int k = 0; k < 12; k++) { int i = c16 + 16 * k; xr[i] = f4nrm(xr[i], inv2, pf4[i]); }
    __syncthreads();
    int wv = tid >> 6, lane = tid & 63;
    int f0 = blockIdx.x * 8 + wv;
    int f1 = f0 + 4;
    float ag0[TT], ag1[TT], au0[TT], au1[TT];
    gemv_row4<192>(reinterpret_cast<const float4*>(gw + (size_t)f0 * DD),
                   reinterpret_cast<const float4*>(gw + (size_t)f1 * DD),
                   reinterpret_cast<const float4*>(uw + (size_t)f0 * DD),
                   reinterpret_cast<const float4*>(uw + (size_t)f1 * DD),
                   xs, lane, ag0, ag1, au0, au1);
    if (lane < TT) {
        {
            float g = ag0[lane], u = au0[lane];
            float inner = 0.7978845608028654f * fmaf(0.044715f * g, g * g, g);
            act[lane * FFF + f0] = 0.5f * g * (1.f + ftanh(inner)) * u;
        }
        {
            float g = ag1[lane], u = au1[lane];
            float inner = 0.7978845608028654f * fmaf(0.044715f * g, g * g, g);
            act[lane * FFF + f1] = 0.5f * g * (1.f + ftanh(inner)) * u;
        }
    }
}

// ---------- K6: down GEMV in f-quarters -> ff partials [4][16][768] ----------
// grid 384 (R15 config): fq = blk&3, dc = blk>>2 (0..95) x 8 rows (pairwise).
__global__ __launch_bounds__(256) void k_down(const float* __restrict__ W, // [768][3072]
                                              const float* __restrict__ act,
                                              float* __restrict__ ffp) {
    __shared__ __align__(16) float xs[TT * DD];
    int tid = threadIdx.x;
    int fq = blockIdx.x & 3, dc = blockIdx.x >> 2;
    {
        const float4* a4 = reinterpret_cast<const float4*>(act);
        float4* s4 = reinterpret_cast<float4*>(xs);
#pragma unroll
        for (int k = 0; k < 12; k++) {
            int i = tid + 256 * k;
            int t = i / 192, cq = i - t * 192;
            s4[i] = a4[t * 768 + fq * 192 + cq];
        }
    }
    __syncthreads();
    int wv = tid >> 6, lane = tid & 63;
    int o0 = dc * 8 + wv;
    int o1 = o0 + 4;
    float acca[TT], accb[TT];
    gemv_row2<192>(reinterpret_cast<const float4*>(W + (size_t)o0 * FFF + fq * 768),
                   reinterpret_cast<const float4*>(W + (size_t)o1 * FFF + fq * 768), xs, lane, acca, accb);
    if (lane < TT) {
        ffp[(fq * TT + lane) * DD + o0] = acca[lane];
        ffp[(fq * TT + lane) * DD + o1] = accb[lane];
    }
}

// ---------- lm_head with fused final-x (quad rows) ----------
// grid 500, 64 rows/block: 4 quads per wave.
__global__ __launch_bounds__(256) void k_lmfused(const float* __restrict__ hB,
                                                 const float* __restrict__ ff,    // [4][16][768]
                                                 const float* __restrict__ pofn25,
                                                 const float* __restrict__ fnw,
                                                 const float* __restrict__ W,     // [32000][768]
                                                 float* __restrict__ logits) {
    __shared__ __align__(16) float xs[TT * DD];
    int tid = threadIdx.x;
    int row = tid >> 4, c16 = tid & 15;
    float4* xr = reinterpret_cast<float4*>(xs) + row * 192;
    const float4* f0 = reinterpret_cast<const float4*>(ff) + row * 192;
    const float4* f1 = f0 + TT * 192;
    const float4* f2 = f1 + TT * 192;
    const float4* f3 = f2 + TT * 192;
    float ss = 0.f;
#pragma unroll
    for (int k = 0; k < 12; k++) {
        int i = c16 + 16 * k;
        float4 v = f4add4(f0[i], f1[i], f2[i], f3[i]);
        xr[i] = v; ss += d4(v, v);
    }
    ss = r16(ss);
    float inv = rsqrtf(ss * (1.f / 768.f) + EPSF);
    const float4* hb4 = reinterpret_cast<const float4*>(hB) + row * 192;
    const float4* po4 = reinterpret_cast<const float4*>(pofn25);
    float ss2 = 0.f;
#pragma unroll
    for (int k = 0; k < 12; k++) {
        int i = c16 + 16 * k;
        float4 v = f4res(hb4[i], xr[i], inv, po4[i]);
        xr[i] = v; ss2 += d4(v, v);
    }
    ss2 = r16(ss2);
    float inv2 = rsqrtf(ss2 * (1.f / 768.f) + EPSF);
    const float4* fn4 = reinterpret_cast<const float4*>(fnw);
#pragma unroll
    for (int k = 0; k < 12; k++) { int i = c16 + 16 * k; xr[i] = f4nrm(xr[i], inv2, fn4[i]); }
    __syncthreads();
    int wv = tid >> 6, lane = tid & 63;
#pragma unroll
    for (int rr = 0; rr < 4; ++rr) {
        int o0 = blockIdx.x * 64 + rr * 16 + wv;
        int o1 = o0 + 4;
        int o2 = o0 + 8;
        int o3 = o0 + 12;
        float acca[TT], accb[TT], accc[TT], accd[TT];
        gemv_row4<192>(reinterpret_cast<const float4*>(W + (size_t)o0 * DD),
                       reinterpret_cast<const float4*>(W + (size_t)o1 * DD),
                       reinterpret_cast<const float4*>(W + (size_t)o2 * DD),
                       reinterpret_cast<const float4*>(W + (size_t)o3 * DD),
                       xs, lane, acca, accb, accc, accd);
        if (lane < TT) {
            logits[lane * VV + o0] = acca[lane];
            logits[lane * VV + o1] = accb[lane];
            logits[lane * VV + o2] = accc[lane];
            logits[lane * VV + o3] = accd[lane];
        }
    }
}

extern "C" void kernel_launch(void* const* d_in, const int* in_sizes, int n_in,
                              void* d_out, int out_size, void* d_ws, size_t ws_size,
                              hipStream_t stream) {
    const float* emb   = (const float*)d_in[0];
    const float* maskg = (const float*)d_in[1];
    const float* maskl = (const float*)d_in[2];
    const float* cosg  = (const float*)d_in[3];
    const float* sing  = (const float*)d_in[4];
    const float* cosl  = (const float*)d_in[5];
    const float* sinl  = (const float*)d_in[6];
    const float* kck   = (const float*)d_in[7];
    const float* kcv   = (const float*)d_in[8];
    const float* pan   = (const float*)d_in[9];
    const float* qkvw  = (const float*)d_in[10];
    const float* qnw   = (const float*)d_in[11];
    const float* knw   = (const float*)d_in[12];
    const float* outw  = (const float*)d_in[13];
    const float* postw = (const float*)d_in[14];
    const float* pfnw  = (const float*)d_in[15];
    const float* gw    = (const float*)d_in[16];
    const float* uw    = (const float*)d_in[17];
    const float* dw    = (const float*)d_in[18];
    const float* pofn  = (const float*)d_in[19];
    const float* fnw   = (const float*)d_in[20];
    const float* lmw   = (const float*)d_in[21];

    float* ws   = (float*)d_ws;
    float* hA   = ws;                 // 12288
    float* hB   = hA + 12288;         // 12288
    float* qkvb = hB + 12288;         // 24576
    float* attnb = qkvb + 24576;      // 16384
    float* yb   = attnb + 16384;      // 12288
    float* act  = yb + 12288;         // 49152
    float* ffp  = act + 49152;        // 49152
    float* part = ffp + 49152;        // 2*65*64*132 = 1,098,240

    float* outp = (float*)d_out;
    float* outK = outp + 512000;
    float* outV = outK + 106496;

    for (int l = 0; l < NL; l++) {
        int loc = ((l + 1) % 6) == 0;
        const float* cosp = loc ? cosl : cosg;
        const float* sinp = loc ? sinl : sing;
        const float* maskp = loc ? maskl : maskg;
        k_qkv<<<192, 256, 0, stream>>>(l == 0 ? 1 : 0, hB, ffp, emb,
                                       l ? (pofn + (size_t)(l - 1) * DD) : pofn,
                                       pan + (size_t)l * DD,
                                       qkvw + (size_t)l * OQKV * DD, qkvb, hA);
        k_attn<<<dim3(NCH, 2, 4), 256, 0, stream>>>(qkvb,
                                                    kck + (size_t)l * 2 * SCCH * HDD,
                                                    kcv + (size_t)l * 2 * HDD * SCCH,
                                                    cosp, sinp, maskp,
                                                    qnw + (size_t)l * HDD, knw + (size_t)l * HDD,
                                                    part,
                                                    outK + (size_t)l * 2 * TT * HDD,
                                                    outV + (size_t)l * 2 * HDD * TT);
        k_combine<<<128, 128, 0, stream>>>(part, attnb);
        k_outproj<<<96, 256, 0, stream>>>(outw + (size_t)l * DD * 1024, attnb, yb);
        k_gateup<<<384, 256, 0, stream>>>(hA, yb, postw + (size_t)l * DD, pfnw + (size_t)l * DD,
                                          gw + (size_t)l * FFF * DD, uw + (size_t)l * FFF * DD,
                                          act, hB);
        k_down<<<384, 256, 0, stream>>>(dw + (size_t)l * DD * FFF, act, ffp);
    }
    k_lmfused<<<500, 256, 0, stream>>>(hB, ffp, pofn + (size_t)25 * DD, fnw, lmw, outp);
}

// Round 19
// 2648.979 us; speedup vs baseline: 1.1382x; 1.0407x over previous
//
#include <hip/hip_runtime.h>
#include <hip/hip_bf16.h>
#include <math.h>

// ---- problem constants ----
#define NL 26
#define TT 16
#define DD 768
#define HDD 128
#define FFF 3072
#define VV 32000
#define SCCH 4096
#define STOT 4112      // SC + T
#define OQKV 1536      // NG*(G+2)*HD
#define EPSF 1e-6f
#define SCALEQ 0.08838834764831845f  // 1/sqrt(128)
#define NCH 65         // 64 cache chunks of 64 + 1 new-token chunk

// native vector type for nontemporal builtins
typedef float nfloat4 __attribute__((ext_vector_type(4)));

// ---------- helpers ----------
__device__ __forceinline__ float d4(const float4 a, const float4 b) {
    return fmaf(a.x, b.x, fmaf(a.y, b.y, fmaf(a.z, b.z, a.w * b.w)));
}
__device__ __forceinline__ float4 fma4(float p, const float4 v, float4 a) {
    return make_float4(fmaf(p, v.x, a.x), fmaf(p, v.y, a.y),
                       fmaf(p, v.z, a.z), fmaf(p, v.w, a.w));
}
__device__ __forceinline__ float4 f4add4(float4 a, float4 b, float4 c, float4 d) {
    return make_float4((a.x + b.x) + (c.x + d.x), (a.y + b.y) + (c.y + d.y),
                       (a.z + b.z) + (c.z + d.z), (a.w + b.w) + (c.w + d.w));
}
// h + f*s*(1+w)
__device__ __forceinline__ float4 f4res(float4 h, float4 f, float s, float4 w) {
    return make_float4(fmaf(f.x * s, 1.f + w.x, h.x), fmaf(f.y * s, 1.f + w.y, h.y),
                       fmaf(f.z * s, 1.f + w.z, h.z), fmaf(f.w * s, 1.f + w.w, h.w));
}
// h*s*(1+w)
__device__ __forceinline__ float4 f4nrm(float4 h, float s, float4 w) {
    return make_float4(h.x * s * (1.f + w.x), h.y * s * (1.f + w.y),
                       h.z * s * (1.f + w.z), h.w * s * (1.f + w.w));
}
__device__ __forceinline__ float r16(float v) {
    v += __shfl_xor(v, 1); v += __shfl_xor(v, 2); v += __shfl_xor(v, 4); v += __shfl_xor(v, 8);
    return v;
}
__device__ __forceinline__ float rwave(float v) {
    v += __shfl_xor(v, 32); v += __shfl_xor(v, 16); v += __shfl_xor(v, 8);
    v += __shfl_xor(v, 4);  v += __shfl_xor(v, 2);  v += __shfl_xor(v, 1);
    return v;
}
// fast tanh: saturation-safe rational form (rel err ~1e-7)
__device__ __forceinline__ float ftanh(float x) {
    float t = __expf(-2.f * fabsf(x));
    float th = (1.f - t) / (1.f + t);
    return copysignf(th, x);
}
// non-temporal float4 load (weights are single-use streams; keep L2 for hot data)
__device__ __forceinline__ float4 ldnt4(const float4* __restrict__ p) {
    nfloat4 v = __builtin_nontemporal_load(reinterpret_cast<const nfloat4*>(p));
    return make_float4(v.x, v.y, v.z, v.w);
}

// GEMV inner, 2 rows interleaved (NT weight loads).
template <int K4>
__device__ __forceinline__ void gemv_row2(const float4* __restrict__ wa,
                                          const float4* __restrict__ wb,
                                          const float* __restrict__ xs, int lane,
                                          float* __restrict__ acca,
                                          float* __restrict__ accb) {
#pragma unroll
    for (int t = 0; t < TT; t++) { acca[t] = 0.f; accb[t] = 0.f; }
    const float4* x4 = reinterpret_cast<const float4*>(xs);
#pragma unroll
    for (int it = 0; it < K4 / 64; ++it) {
        float4 a = ldnt4(&wa[it * 64 + lane]);
        float4 b = ldnt4(&wb[it * 64 + lane]);
#pragma unroll
        for (int t = 0; t < TT; t++) {
            float4 x = x4[t * K4 + it * 64 + lane];
            acca[t] = fmaf(a.x, x.x, fmaf(a.y, x.y, fmaf(a.z, x.z, fmaf(a.w, x.w, acca[t]))));
            accb[t] = fmaf(b.x, x.x, fmaf(b.y, x.y, fmaf(b.z, x.z, fmaf(b.w, x.w, accb[t]))));
        }
    }
#pragma unroll
    for (int t = 0; t < TT; t++) { acca[t] = rwave(acca[t]); accb[t] = rwave(accb[t]); }
}

// GEMV inner, 4 rows interleaved (one shared x pass, NT weight loads).
template <int K4>
__device__ __forceinline__ void gemv_row4(const float4* __restrict__ wa,
                                          const float4* __restrict__ wb,
                                          const float4* __restrict__ wc,
                                          const float4* __restrict__ wd,
                                          const float* __restrict__ xs, int lane,
                                          float* __restrict__ acca, float* __restrict__ accb,
                                          float* __restrict__ accc, float* __restrict__ accd) {
#pragma unroll
    for (int t = 0; t < TT; t++) { acca[t] = 0.f; accb[t] = 0.f; accc[t] = 0.f; accd[t] = 0.f; }
    const float4* x4 = reinterpret_cast<const float4*>(xs);
#pragma unroll
    for (int it = 0; it < K4 / 64; ++it) {
        float4 a = ldnt4(&wa[it * 64 + lane]);
        float4 b = ldnt4(&wb[it * 64 + lane]);
        float4 c = ldnt4(&wc[it * 64 + lane]);
        float4 d = ldnt4(&wd[it * 64 + lane]);
#pragma unroll
        for (int t = 0; t < TT; t++) {
            float4 x = x4[t * K4 + it * 64 + lane];
            acca[t] = fmaf(a.x, x.x, fmaf(a.y, x.y, fmaf(a.z, x.z, fmaf(a.w, x.w, acca[t]))));
            accb[t] = fmaf(b.x, x.x, fmaf(b.y, x.y, fmaf(b.z, x.z, fmaf(b.w, x.w, accb[t]))));
            accc[t] = fmaf(c.x, x.x, fmaf(c.y, x.y, fmaf(c.z, x.z, fmaf(c.w, x.w, accc[t]))));
            accd[t] = fmaf(d.x, x.x, fmaf(d.y, x.y, fmaf(d.z, x.z, fmaf(d.w, x.w, accd[t]))));
        }
    }
#pragma unroll
    for (int t = 0; t < TT; t++) {
        acca[t] = rwave(acca[t]); accb[t] = rwave(accb[t]);
        accc[t] = rwave(accc[t]); accd[t] = rwave(accd[t]);
    }
}

// ---------- K1: (deferred ff residual) + pre-attn rmsnorm + QKV GEMV ----------
// grid 192, 8 rows/block: wave wv owns pair (blk*8+wv, blk*8+wv+4).
__global__ __launch_bounds__(256) void k_qkv(const int first,
                                             const float* __restrict__ hB,
                                             const float* __restrict__ ff,   // [4][16][768]
                                             const float* __restrict__ emb,
                                             const float* __restrict__ pofn_prev,
                                             const float* __restrict__ pan,
                                             const float* __restrict__ W,    // [1536][768]
                                             float* __restrict__ qkvo,       // [16][1536]
                                             float* __restrict__ hA) {
    __shared__ __align__(16) float xs[TT * DD];
    const int tid = threadIdx.x;
    const int row = tid >> 4, c16 = tid & 15;
    float4* xr = reinterpret_cast<float4*>(xs) + row * 192;
    float4* hA4 = reinterpret_cast<float4*>(hA) + row * 192;
    if (first) {
        const float4* e4 = reinterpret_cast<const float4*>(emb) + row * 192;
        float ss = 0.f;
#pragma unroll
        for (int k = 0; k < 12; k++) { int i = c16 + 16 * k; float4 v = e4[i]; xr[i] = v; ss += d4(v, v); }
        ss = r16(ss);
        float inv = rsqrtf(ss * (1.f / 768.f) + EPSF);
        if (blockIdx.x == 0) {
#pragma unroll
            for (int k = 0; k < 12; k++) { int i = c16 + 16 * k; hA4[i] = xr[i]; }
        }
        const float4* p4 = reinterpret_cast<const float4*>(pan);
#pragma unroll
        for (int k = 0; k < 12; k++) { int i = c16 + 16 * k; xr[i] = f4nrm(xr[i], inv, p4[i]); }
    } else {
        const float4* f0 = reinterpret_cast<const float4*>(ff) + row * 192;
        const float4* f1 = f0 + TT * 192;
        const float4* f2 = f1 + TT * 192;
        const float4* f3 = f2 + TT * 192;
        float ss = 0.f;
#pragma unroll
        for (int k = 0; k < 12; k++) {
            int i = c16 + 16 * k;
            float4 v = f4add4(f0[i], f1[i], f2[i], f3[i]);
            xr[i] = v; ss += d4(v, v);
        }
        ss = r16(ss);
        float inv = rsqrtf(ss * (1.f / 768.f) + EPSF);
        const float4* hb4 = reinterpret_cast<const float4*>(hB) + row * 192;
        const float4* po4 = reinterpret_cast<const float4*>(pofn_prev);
        float ss2 = 0.f;
#pragma unroll
        for (int k = 0; k < 12; k++) {
            int i = c16 + 16 * k;
            float4 v = f4res(hb4[i], xr[i], inv, po4[i]);
            xr[i] = v; ss2 += d4(v, v);
            if (blockIdx.x == 0) hA4[i] = v;
        }
        ss2 = r16(ss2);
        float inv2 = rsqrtf(ss2 * (1.f / 768.f) + EPSF);
        const float4* p4 = reinterpret_cast<const float4*>(pan);
#pragma unroll
        for (int k = 0; k < 12; k++) { int i = c16 + 16 * k; xr[i] = f4nrm(xr[i], inv2, p4[i]); }
    }
    __syncthreads();
    const int wv = tid >> 6, lane = tid & 63;
    const int o0 = blockIdx.x * 8 + wv;
    const int o1 = o0 + 4;
    float acca[TT], accb[TT];
    gemv_row2<192>(reinterpret_cast<const float4*>(W + (size_t)o0 * DD),
                   reinterpret_cast<const float4*>(W + (size_t)o1 * DD), xs, lane, acca, accb);
    if (lane < TT) {
        qkvo[lane * OQKV + o0] = acca[lane];
        qkvo[lane * OQKV + o1] = accb[lane];
    }
}

// ---------- K2: attention partials, 16 q-rows per block ----------
// grid (65, 2, 4). Scores: lane l16 = tid&15 owns positions i = 16j + l16 outright
// (full 128-d dot from LDS; q-row is a 16-lane broadcast, K rows 2-way bank-aliased).
// Zero shuffles in QK. Q parked in dedicated qs buffer (kvb gets overwritten by K).
__global__ __launch_bounds__(256) void k_attn(const float* __restrict__ qkv,
                                              const float* __restrict__ kc,  // [2][4096][128]
                                              const float* __restrict__ vc,  // [2][128][4096]
                                              const float* __restrict__ cosp,
                                              const float* __restrict__ sinp,
                                              const float* __restrict__ mask, // [16][4112]
                                              const float* __restrict__ qnw,
                                              const float* __restrict__ knw,
                                              float* __restrict__ part,
                                              float* __restrict__ kout,   // [2][16][128]
                                              float* __restrict__ vout)   // [2][128][16]
{
    __shared__ __align__(16) float kvb[64 * 132];
    __shared__ __align__(16) float qs[16 * 132];
    __shared__ __align__(16) float pls[16 * 68];
    const int tid = threadIdx.x;
    const int c = blockIdx.x;
    const int ng = blockIdx.y;
    const int rq = blockIdx.z;
    const bool newc = (c == 64);

    // --- Q build into qs rows 0..15 (16 rows x 16 threads, 8 dims each)
    {
        int rl = tid >> 4, c16 = tid & 15;
        int r = rq * 16 + rl;
        int tsrc = r >> 2, g = r & 3;
        const float* src = qkv + tsrc * OQKV + ng * 768 + g * 128;
        float ss = 0.f;
#pragma unroll
        for (int j = 0; j < 8; j++) { float v = src[c16 * 8 + j]; ss += v * v; }
        ss = r16(ss);
        float inv = rsqrtf(ss * (1.f / 128.f) + EPSF);
        int pos = r & 15;
        const float* cp = cosp + pos * 128;
        const float* sp = sinp + pos * 128;
#pragma unroll
        for (int j = 0; j < 8; j++) {
            int d = c16 * 8 + j;
            float xn = src[d] * inv * (1.f + qnw[d]);
            float out;
            if (d < 64) { float pr = src[d + 64] * inv * (1.f + qnw[d + 64]); out = xn * cp[d] - pr * sp[d]; }
            else        { float pr = src[d - 64] * inv * (1.f + qnw[d - 64]); out = xn * cp[d] + pr * sp[d]; }
            qs[rl * 132 + d] = out;
        }
    }
    // --- K stage (no dependency on Q build; one sync covers both)
    if (!newc) {
        int rowk = tid >> 2, q4i = tid & 3;
        const float4* k4 = reinterpret_cast<const float4*>(kc + (size_t)(ng * SCCH + c * 64 + rowk) * 128);
#pragma unroll
        for (int k = 0; k < 8; k++) {
            float4 v = k4[q4i * 8 + k];
            *reinterpret_cast<float4*>(&kvb[rowk * 132 + 4 * (q4i * 8 + k)]) = v;
        }
    } else {
        int t = tid >> 4, c16 = tid & 15;
        const float* src = qkv + t * OQKV + ng * 768 + 4 * 128;
        float ss = 0.f;
#pragma unroll
        for (int j = 0; j < 8; j++) { float v = src[c16 * 8 + j]; ss += v * v; }
        ss = r16(ss);
        float inv = rsqrtf(ss * (1.f / 128.f) + EPSF);
        const float* cp = cosp + t * 128;
        const float* sp = sinp + t * 128;
#pragma unroll
        for (int j = 0; j < 8; j++) {
            int d = c16 * 8 + j;
            float xn = src[d] * inv * (1.f + knw[d]);
            float out;
            if (d < 64) { float pr = src[d + 64] * inv * (1.f + knw[d + 64]); out = xn * cp[d] - pr * sp[d]; }
            else        { float pr = src[d - 64] * inv * (1.f + knw[d - 64]); out = xn * cp[d] + pr * sp[d]; }
            kvb[t * 132 + d] = out;
            if (rq == 0) kout[(ng * TT + t) * 128 + d] = out;
        }
        for (int i = tid; i < 48 * 132; i += 256) kvb[16 * 132 + i] = 0.f;
    }
    __syncthreads();
    // --- scores: lane (rr, l16) computes full dot for positions i = 16j + l16
    const int rr = tid >> 4;
    const int l16 = tid & 15;
    const int r = rq * 16 + rr;
    const int pos = r & 15;
    const int cnt_pos = newc ? TT : 64;
    const float* mrow = mask + pos * STOT + c * 64;
    const float4* qrow = reinterpret_cast<const float4*>(qs + rr * 132);
    float* prow = pls + rr * 68;
#pragma unroll 2
    for (int j = 0; j < 4; j++) {
        int i = 16 * j + l16;
        const float4* krow = reinterpret_cast<const float4*>(kvb + i * 132);
        float p = 0.f;
#pragma unroll 4
        for (int w = 0; w < 32; w++) p += d4(qrow[w], krow[w]);
        if (i < cnt_pos) {
            p *= SCALEQ;
            p = 50.f * ftanh(p * 0.02f);
            p += mrow[i];
        } else {
            p = -1e30f;
        }
        prow[i] = p;   // owner-private slot
    }
    // --- softmax: redundant per-lane over the LDS row (wave-local, in-order)
    {
        const float4* prow4 = reinterpret_cast<const float4*>(prow);
        float m = -1e30f;
#pragma unroll 4
        for (int w = 0; w < 16; w++) {
            float4 v = prow4[w];
            m = fmaxf(m, fmaxf(fmaxf(v.x, v.y), fmaxf(v.z, v.w)));
        }
        float lsum = 0.f;
#pragma unroll 4
        for (int w = 0; w < 16; w++) {
            float4 v = prow4[w];
            lsum += (__expf(v.x - m) + __expf(v.y - m)) + (__expf(v.z - m) + __expf(v.w - m));
        }
        // exp write-back: lane owns slots i = 16j + l16 (disjoint)
#pragma unroll 2
        for (int j = 0; j < 4; j++) {
            int i = 16 * j + l16;
            prow[i] = __expf(prow[i] - m);
        }
        if (l16 == 0) {
            float* pb = part + (size_t)((ng * NCH + c) * 64 + r) * 132;
            pb[128] = m; pb[129] = lsum;
        }
    }
    __syncthreads();
    // --- V stage (reuse kvb) -> [pos][dim]
    if (!newc) {
        int d = tid >> 1, hv = tid & 1;
        const float4* v4 = reinterpret_cast<const float4*>(vc + (size_t)(ng * 128 + d) * SCCH + c * 64);
#pragma unroll
        for (int k = 0; k < 8; k++) {
            float4 v = v4[hv * 8 + k];
            int sl = hv * 32 + 4 * k;
            kvb[(sl + 0) * 132 + d] = v.x;
            kvb[(sl + 1) * 132 + d] = v.y;
            kvb[(sl + 2) * 132 + d] = v.z;
            kvb[(sl + 3) * 132 + d] = v.w;
        }
    } else {
        int t = tid >> 4, c16 = tid & 15;
        const float* src = qkv + t * OQKV + ng * 768 + 5 * 128;
#pragma unroll
        for (int j = 0; j < 8; j++) {
            int d = c16 * 8 + j;
            float v = src[d];
            kvb[t * 132 + d] = v;
            if (rq == 0) vout[(ng * 128 + d) * TT + t] = v;
        }
    }
    __syncthreads();
    // --- PV (octet structure: dims dq*4+32m, positions split by half; merge via shfl_xor(8))
    const int half = (tid >> 3) & 1;
    const int dq = tid & 7;
    float4 accv[4];
#pragma unroll
    for (int m2 = 0; m2 < 4; m2++) accv[m2] = make_float4(0.f, 0.f, 0.f, 0.f);
#pragma unroll 4
    for (int jj = 0; jj < 32; jj++) {
        int i = half * 32 + jj;
        float p = prow[i];
        const float4* v4 = reinterpret_cast<const float4*>(kvb + i * 132);
        accv[0] = fma4(p, v4[dq], accv[0]);
        accv[1] = fma4(p, v4[dq + 8], accv[1]);
        accv[2] = fma4(p, v4[dq + 16], accv[2]);
        accv[3] = fma4(p, v4[dq + 24], accv[3]);
    }
#pragma unroll
    for (int m2 = 0; m2 < 4; m2++) {
        accv[m2].x += __shfl_xor(accv[m2].x, 8);
        accv[m2].y += __shfl_xor(accv[m2].y, 8);
        accv[m2].z += __shfl_xor(accv[m2].z, 8);
        accv[m2].w += __shfl_xor(accv[m2].w, 8);
    }
    if (half == 0) {
        float* pb = part + (size_t)((ng * NCH + c) * 64 + r) * 132;
        float4* pb4 = reinterpret_cast<float4*>(pb);
        pb4[dq] = accv[0]; pb4[dq + 8] = accv[1]; pb4[dq + 16] = accv[2]; pb4[dq + 24] = accv[3];
    }
}

// ---------- K3: combine partials -> attn [t][h*128+d] (unchanged) ----------
__global__ __launch_bounds__(128) void k_combine(const float* __restrict__ part,
                                                 float* __restrict__ attn) {
    __shared__ float marr[NCH], larr[NCH], warr[NCH];
    __shared__ __align__(16) float mrg[4][128];
    int blk = blockIdx.x;
    int ng = blk >> 6, r = blk & 63;
    int tid = threadIdx.x;
    const float* pb = part + (size_t)(ng * NCH * 64 + r) * 132;
    if (tid < NCH) {
        marr[tid] = pb[(size_t)tid * 64 * 132 + 128];
        larr[tid] = pb[(size_t)tid * 64 * 132 + 129];
    }
    __syncthreads();
    float M = -1e30f;
#pragma unroll 4
    for (int cc = 0; cc < NCH; cc++) M = fmaxf(M, marr[cc]);
    if (tid < NCH) warr[tid] = __expf(marr[tid] - M);
    __syncthreads();
    float Lsum = 0.f;
#pragma unroll 4
    for (int cc = 0; cc < NCH; cc++) Lsum = fmaf(larr[cc], warr[cc], Lsum);
    int q = tid >> 5, dd = tid & 31;
    float4 A4 = make_float4(0.f, 0.f, 0.f, 0.f);
    for (int cc = q; cc < NCH; cc += 4) {
        const float4* pa = reinterpret_cast<const float4*>(pb + (size_t)cc * 64 * 132);
        A4 = fma4(warr[cc], pa[dd], A4);
    }
    *reinterpret_cast<float4*>(&mrg[q][dd * 4]) = A4;
    __syncthreads();
    int d = tid;
    float A = (mrg[0][d] + mrg[1][d]) + (mrg[2][d] + mrg[3][d]);
    int h = ng * 4 + (r >> 4), pos = r & 15;
    attn[pos * 1024 + h * 128 + d] = A / Lsum;
}

// ---------- K4: out projection (pairwise) ----------
__global__ __launch_bounds__(256) void k_outproj(const float* __restrict__ W, // [768][1024]
                                                 const float* __restrict__ attn,
                                                 float* __restrict__ y) {
    int tid = threadIdx.x;
    int wv = tid >> 6, lane = tid & 63;
    int o0 = blockIdx.x * 8 + wv;
    int o1 = o0 + 4;
    float acca[TT], accb[TT];
    gemv_row2<256>(reinterpret_cast<const float4*>(W + (size_t)o0 * 1024),
                   reinterpret_cast<const float4*>(W + (size_t)o1 * 1024), attn, lane, acca, accb);
    if (lane < TT) {
        y[lane * DD + o0] = acca[lane];
        y[lane * DD + o1] = accb[lane];
    }
}

// ---------- K5: post-attn residual+norm, pre-ff norm, gate/up GEMV4 + GELU*up ----------
// grid 384, 8 f-rows/block.
__global__ __launch_bounds__(256) void k_gateup(const float* __restrict__ hA,
                                                const float* __restrict__ y,
                                                const float* __restrict__ postw,
                                                const float* __restrict__ pfn,
                                                const float* __restrict__ gw,
                                                const float* __restrict__ uw,
                                                float* __restrict__ act,
                                                float* __restrict__ hB) {
    __shared__ __align__(16) float xs[TT * DD];
    int tid = threadIdx.x;
    int row = tid >> 4, c16 = tid & 15;
    float4* xr = reinterpret_cast<float4*>(xs) + row * 192;
    const float4* y4 = reinterpret_cast<const float4*>(y) + row * 192;
    float ss = 0.f;
#pragma unroll
    for (int k = 0; k < 12; k++) { int i = c16 + 16 * k; float4 v = y4[i]; xr[i] = v; ss += d4(v, v); }
    ss = r16(ss);
    float inv = rsqrtf(ss * (1.f / 768.f) + EPSF);
    const float4* ha4 = reinterpret_cast<const float4*>(hA) + row * 192;
    const float4* pw4 = reinterpret_cast<const float4*>(postw);
    float4* hB4 = reinterpret_cast<float4*>(hB) + row * 192;
    float ss2 = 0.f;
#pragma unroll
    for (int k = 0; k < 12; k++) {
        int i = c16 + 16 * k;
        float4 v = f4res(ha4[i], xr[i], inv, pw4[i]);
        xr[i] = v; ss2 += d4(v, v);
        if (blockIdx.x == 0) hB4[i] = v;
    }
    ss2 = r16(ss2);
    float inv2 = rsqrtf(ss2 * (1.f / 768.f) + EPSF);
    const float4* pf4 = reinterpret_cast<const float4*>(pfn);
#pragma unroll
    for (int k = 0; k < 12; k++) { int i = c16 + 16 * k; xr[i] = f4nrm(xr[i], inv2, pf4[i]); }
    __syncthreads();
    int wv = tid >> 6, lane = tid & 63;
    int f0 = blockIdx.x * 8 + wv;
    int f1 = f0 + 4;
    float ag0[TT], ag1[TT], au0[TT], au1[TT];
    gemv_row4<192>(reinterpret_cast<const float4*>(gw + (size_t)f0 * DD),
                   reinterpret_cast<const float4*>(gw + (size_t)f1 * DD),
                   reinterpret_cast<const float4*>(uw + (size_t)f0 * DD),
                   reinterpret_cast<const float4*>(uw + (size_t)f1 * DD),
                   xs, lane, ag0, ag1, au0, au1);
    if (lane < TT) {
        {
            float g = ag0[lane], u = au0[lane];
            float inner = 0.7978845608028654f * fmaf(0.044715f * g, g * g, g);
            act[lane * FFF + f0] = 0.5f * g * (1.f + ftanh(inner)) * u;
        }
        {
            float g = ag1[lane], u = au1[lane];
            float inner = 0.7978845608028654f * fmaf(0.044715f * g, g * g, g);
            act[lane * FFF + f1] = 0.5f * g * (1.f + ftanh(inner)) * u;
        }
    }
}

// ---------- K6: down GEMV in f-quarters -> ff partials [4][16][768] ----------
// grid 384: fq = blk&3, dc = blk>>2 (0..95) x 8 rows (pairwise).
__global__ __launch_bounds__(256) void k_down(const float* __restrict__ W, // [768][3072]
                                              const float* __restrict__ act,
                                              float* __restrict__ ffp) {
    __shared__ __align__(16) float xs[TT * DD];
    int tid = threadIdx.x;
    int fq = blockIdx.x & 3, dc = blockIdx.x >> 2;
    {
        const float4* a4 = reinterpret_cast<const float4*>(act);
        float4* s4 = reinterpret_cast<float4*>(xs);
#pragma unroll
        for (int k = 0; k < 12; k++) {
            int i = tid + 256 * k;
            int t = i / 192, cq = i - t * 192;
            s4[i] = a4[t * 768 + fq * 192 + cq];
        }
    }
    __syncthreads();
    int wv = tid >> 6, lane = tid & 63;
    int o0 = dc * 8 + wv;
    int o1 = o0 + 4;
    float acca[TT], accb[TT];
    gemv_row2<192>(reinterpret_cast<const float4*>(W + (size_t)o0 * FFF + fq * 768),
                   reinterpret_cast<const float4*>(W + (size_t)o1 * FFF + fq * 768), xs, lane, acca, accb);
    if (lane < TT) {
        ffp[(fq * TT + lane) * DD + o0] = acca[lane];
        ffp[(fq * TT + lane) * DD + o1] = accb[lane];
    }
}

// ---------- lm_head with fused final-x (quad rows) ----------
// grid 500, 64 rows/block: 4 quads per wave.
__global__ __launch_bounds__(256) void k_lmfused(const float* __restrict__ hB,
                                                 const float* __restrict__ ff,    // [4][16][768]
                                                 const float* __restrict__ pofn25,
                                                 const float* __restrict__ fnw,
                                                 const float* __restrict__ W,     // [32000][768]
                                                 float* __restrict__ logits) {
    __shared__ __align__(16) float xs[TT * DD];
    int tid = threadIdx.x;
    int row = tid >> 4, c16 = tid & 15;
    float4* xr = reinterpret_cast<float4*>(xs) + row * 192;
    const float4* f0 = reinterpret_cast<const float4*>(ff) + row * 192;
    const float4* f1 = f0 + TT * 192;
    const float4* f2 = f1 + TT * 192;
    const float4* f3 = f2 + TT * 192;
    float ss = 0.f;
#pragma unroll
    for (int k = 0; k < 12; k++) {
        int i = c16 + 16 * k;
        float4 v = f4add4(f0[i], f1[i], f2[i], f3[i]);
        xr[i] = v; ss += d4(v, v);
    }
    ss = r16(ss);
    float inv = rsqrtf(ss * (1.f / 768.f) + EPSF);
    const float4* hb4 = reinterpret_cast<const float4*>(hB) + row * 192;
    const float4* po4 = reinterpret_cast<const float4*>(pofn25);
    float ss2 = 0.f;
#pragma unroll
    for (int k = 0; k < 12; k++) {
        int i = c16 + 16 * k;
        float4 v = f4res(hb4[i], xr[i], inv, po4[i]);
        xr[i] = v; ss2 += d4(v, v);
    }
    ss2 = r16(ss2);
    float inv2 = rsqrtf(ss2 * (1.f / 768.f) + EPSF);
    const float4* fn4 = reinterpret_cast<const float4*>(fnw);
#pragma unroll
    for (int k = 0; k < 12; k++) { int i = c16 + 16 * k; xr[i] = f4nrm(xr[i], inv2, fn4[i]); }
    __syncthreads();
    int wv = tid >> 6, lane = tid & 63;
#pragma unroll
    for (int rr = 0; rr < 4; ++rr) {
        int o0 = blockIdx.x * 64 + rr * 16 + wv;
        int o1 = o0 + 4;
        int o2 = o0 + 8;
        int o3 = o0 + 12;
        float acca[TT], accb[TT], accc[TT], accd[TT];
        gemv_row4<192>(reinterpret_cast<const float4*>(W + (size_t)o0 * DD),
                       reinterpret_cast<const float4*>(W + (size_t)o1 * DD),
                       reinterpret_cast<const float4*>(W + (size_t)o2 * DD),
                       reinterpret_cast<const float4*>(W + (size_t)o3 * DD),
                       xs, lane, acca, accb, accc, accd);
        if (lane < TT) {
            logits[lane * VV + o0] = acca[lane];
            logits[lane * VV + o1] = accb[lane];
            logits[lane * VV + o2] = accc[lane];
            logits[lane * VV + o3] = accd[lane];
        }
    }
}

extern "C" void kernel_launch(void* const* d_in, const int* in_sizes, int n_in,
                              void* d_out, int out_size, void* d_ws, size_t ws_size,
                              hipStream_t stream) {
    const float* emb   = (const float*)d_in[0];
    const float* maskg = (const float*)d_in[1];
    const float* maskl = (const float*)d_in[2];
    const float* cosg  = (const float*)d_in[3];
    const float* sing  = (const float*)d_in[4];
    const float* cosl  = (const float*)d_in[5];
    const float* sinl  = (const float*)d_in[6];
    const float* kck   = (const float*)d_in[7];
    const float* kcv   = (const float*)d_in[8];
    const float* pan   = (const float*)d_in[9];
    const float* qkvw  = (const float*)d_in[10];
    const float* qnw   = (const float*)d_in[11];
    const float* knw   = (const float*)d_in[12];
    const float* outw  = (const float*)d_in[13];
    const float* postw = (const float*)d_in[14];
    const float* pfnw  = (const float*)d_in[15];
    const float* gw    = (const float*)d_in[16];
    const float* uw    = (const float*)d_in[17];
    const float* dw    = (const float*)d_in[18];
    const float* pofn  = (const float*)d_in[19];
    const float* fnw   = (const float*)d_in[20];
    const float* lmw   = (const float*)d_in[21];

    float* ws   = (float*)d_ws;
    float* hA   = ws;                 // 12288
    float* hB   = hA + 12288;         // 12288
    float* qkvb = hB + 12288;         // 24576
    float* attnb = qkvb + 24576;      // 16384
    float* yb   = attnb + 16384;      // 12288
    float* act  = yb + 12288;         // 49152
    float* ffp  = act + 49152;        // 49152
    float* part = ffp + 49152;        // 2*65*64*132 = 1,098,240

    float* outp = (float*)d_out;
    float* outK = outp + 512000;
    float* outV = outK + 106496;

    for (int l = 0; l < NL; l++) {
        int loc = ((l + 1) % 6) == 0;
        const float* cosp = loc ? cosl : cosg;
        const float* sinp = loc ? sinl : sing;
        const float* maskp = loc ? maskl : maskg;
        k_qkv<<<192, 256, 0, stream>>>(l == 0 ? 1 : 0, hB, ffp, emb,
                                       l ? (pofn + (size_t)(l - 1) * DD) : pofn,
                                       pan + (size_t)l * DD,
                                       qkvw + (size_t)l * OQKV * DD, qkvb, hA);
        k_attn<<<dim3(NCH, 2, 4), 256, 0, stream>>>(qkvb,
                                                    kck + (size_t)l * 2 * SCCH * HDD,
                                                    kcv + (size_t)l * 2 * HDD * SCCH,
                                                    cosp, sinp, maskp,
                                                    qnw + (size_t)l * HDD, knw + (size_t)l * HDD,
                                                    part,
                                                    outK + (size_t)l * 2 * TT * HDD,
                                                    outV + (size_t)l * 2 * HDD * TT);
        k_combine<<<128, 128, 0, stream>>>(part, attnb);
        k_outproj<<<96, 256, 0, stream>>>(outw + (size_t)l * DD * 1024, attnb, yb);
        k_gateup<<<384, 256, 0, stream>>>(hA, yb, postw + (size_t)l * DD, pfnw + (size_t)l * DD,
                                          gw + (size_t)l * FFF * DD, uw + (size_t)l * FFF * DD,
                                          act, hB);
        k_down<<<384, 256, 0, stream>>>(dw + (size_t)l * DD * FFF, act, ffp);
    }
    k_lmfused<<<500, 256, 0, stream>>>(hB, ffp, pofn + (size_t)25 * DD, fnw, lmw, outp);
}

// Round 20
// 2592.938 us; speedup vs baseline: 1.1628x; 1.0216x over previous
//
#include <hip/hip_runtime.h>
#include <hip/hip_bf16.h>
#include <math.h>

// ---- problem constants ----
#define NL 26
#define TT 16
#define DD 768
#define HDD 128
#define FFF 3072
#define VV 32000
#define SCCH 4096
#define STOT 4112      // SC + T
#define OQKV 1536      // NG*(G+2)*HD
#define EPSF 1e-6f
#define SCALEQ 0.08838834764831845f  // 1/sqrt(128)
#define NCH 65         // 64 cache chunks of 64 + 1 new-token chunk
#define M0 12.0f       // fixed softmax max: |softcap| <= 11.8 (normed q,k), masks <= 0

// native vector type for nontemporal builtins
typedef float nfloat4 __attribute__((ext_vector_type(4)));

// ---------- helpers ----------
__device__ __forceinline__ float d4(const float4 a, const float4 b) {
    return fmaf(a.x, b.x, fmaf(a.y, b.y, fmaf(a.z, b.z, a.w * b.w)));
}
__device__ __forceinline__ float4 fma4(float p, const float4 v, float4 a) {
    return make_float4(fmaf(p, v.x, a.x), fmaf(p, v.y, a.y),
                       fmaf(p, v.z, a.z), fmaf(p, v.w, a.w));
}
__device__ __forceinline__ float4 f4add4(float4 a, float4 b, float4 c, float4 d) {
    return make_float4((a.x + b.x) + (c.x + d.x), (a.y + b.y) + (c.y + d.y),
                       (a.z + b.z) + (c.z + d.z), (a.w + b.w) + (c.w + d.w));
}
// h + f*s*(1+w)
__device__ __forceinline__ float4 f4res(float4 h, float4 f, float s, float4 w) {
    return make_float4(fmaf(f.x * s, 1.f + w.x, h.x), fmaf(f.y * s, 1.f + w.y, h.y),
                       fmaf(f.z * s, 1.f + w.z, h.z), fmaf(f.w * s, 1.f + w.w, h.w));
}
// h*s*(1+w)
__device__ __forceinline__ float4 f4nrm(float4 h, float s, float4 w) {
    return make_float4(h.x * s * (1.f + w.x), h.y * s * (1.f + w.y),
                       h.z * s * (1.f + w.z), h.w * s * (1.f + w.w));
}
__device__ __forceinline__ float r16(float v) {
    v += __shfl_xor(v, 1); v += __shfl_xor(v, 2); v += __shfl_xor(v, 4); v += __shfl_xor(v, 8);
    return v;
}
__device__ __forceinline__ float rwave(float v) {
    v += __shfl_xor(v, 32); v += __shfl_xor(v, 16); v += __shfl_xor(v, 8);
    v += __shfl_xor(v, 4);  v += __shfl_xor(v, 2);  v += __shfl_xor(v, 1);
    return v;
}
// fast tanh: saturation-safe rational form (rel err ~1e-7)
__device__ __forceinline__ float ftanh(float x) {
    float t = __expf(-2.f * fabsf(x));
    float th = (1.f - t) / (1.f + t);
    return copysignf(th, x);
}
// non-temporal float4 load (weights are single-use streams; keep L2 for hot data)
__device__ __forceinline__ float4 ldnt4(const float4* __restrict__ p) {
    nfloat4 v = __builtin_nontemporal_load(reinterpret_cast<const nfloat4*>(p));
    return make_float4(v.x, v.y, v.z, v.w);
}

// GEMV inner, 2 rows interleaved (NT weight loads).
template <int K4>
__device__ __forceinline__ void gemv_row2(const float4* __restrict__ wa,
                                          const float4* __restrict__ wb,
                                          const float* __restrict__ xs, int lane,
                                          float* __restrict__ acca,
                                          float* __restrict__ accb) {
#pragma unroll
    for (int t = 0; t < TT; t++) { acca[t] = 0.f; accb[t] = 0.f; }
    const float4* x4 = reinterpret_cast<const float4*>(xs);
#pragma unroll
    for (int it = 0; it < K4 / 64; ++it) {
        float4 a = ldnt4(&wa[it * 64 + lane]);
        float4 b = ldnt4(&wb[it * 64 + lane]);
#pragma unroll
        for (int t = 0; t < TT; t++) {
            float4 x = x4[t * K4 + it * 64 + lane];
            acca[t] = fmaf(a.x, x.x, fmaf(a.y, x.y, fmaf(a.z, x.z, fmaf(a.w, x.w, acca[t]))));
            accb[t] = fmaf(b.x, x.x, fmaf(b.y, x.y, fmaf(b.z, x.z, fmaf(b.w, x.w, accb[t]))));
        }
    }
#pragma unroll
    for (int t = 0; t < TT; t++) { acca[t] = rwave(acca[t]); accb[t] = rwave(accb[t]); }
}

// GEMV inner, 4 rows interleaved (one shared x pass, NT weight loads).
template <int K4>
__device__ __forceinline__ void gemv_row4(const float4* __restrict__ wa,
                                          const float4* __restrict__ wb,
                                          const float4* __restrict__ wc,
                                          const float4* __restrict__ wd,
                                          const float* __restrict__ xs, int lane,
                                          float* __restrict__ acca, float* __restrict__ accb,
                                          float* __restrict__ accc, float* __restrict__ accd) {
#pragma unroll
    for (int t = 0; t < TT; t++) { acca[t] = 0.f; accb[t] = 0.f; accc[t] = 0.f; accd[t] = 0.f; }
    const float4* x4 = reinterpret_cast<const float4*>(xs);
#pragma unroll
    for (int it = 0; it < K4 / 64; ++it) {
        float4 a = ldnt4(&wa[it * 64 + lane]);
        float4 b = ldnt4(&wb[it * 64 + lane]);
        float4 c = ldnt4(&wc[it * 64 + lane]);
        float4 d = ldnt4(&wd[it * 64 + lane]);
#pragma unroll
        for (int t = 0; t < TT; t++) {
            float4 x = x4[t * K4 + it * 64 + lane];
            acca[t] = fmaf(a.x, x.x, fmaf(a.y, x.y, fmaf(a.z, x.z, fmaf(a.w, x.w, acca[t]))));
            accb[t] = fmaf(b.x, x.x, fmaf(b.y, x.y, fmaf(b.z, x.z, fmaf(b.w, x.w, accb[t]))));
            accc[t] = fmaf(c.x, x.x, fmaf(c.y, x.y, fmaf(c.z, x.z, fmaf(c.w, x.w, accc[t]))));
            accd[t] = fmaf(d.x, x.x, fmaf(d.y, x.y, fmaf(d.z, x.z, fmaf(d.w, x.w, accd[t]))));
        }
    }
#pragma unroll
    for (int t = 0; t < TT; t++) {
        acca[t] = rwave(acca[t]); accb[t] = rwave(accb[t]);
        accc[t] = rwave(accc[t]); accd[t] = rwave(accd[t]);
    }
}

// ---------- K1: (deferred ff residual) + pre-attn rmsnorm + QKV GEMV ----------
// grid 192, 8 rows/block: wave wv owns pair (blk*8+wv, blk*8+wv+4).
__global__ __launch_bounds__(256) void k_qkv(const int first,
                                             const float* __restrict__ hB,
                                             const float* __restrict__ ff,   // [4][16][768]
                                             const float* __restrict__ emb,
                                             const float* __restrict__ pofn_prev,
                                             const float* __restrict__ pan,
                                             const float* __restrict__ W,    // [1536][768]
                                             float* __restrict__ qkvo,       // [16][1536]
                                             float* __restrict__ hA) {
    __shared__ __align__(16) float xs[TT * DD];
    const int tid = threadIdx.x;
    const int row = tid >> 4, c16 = tid & 15;
    float4* xr = reinterpret_cast<float4*>(xs) + row * 192;
    float4* hA4 = reinterpret_cast<float4*>(hA) + row * 192;
    if (first) {
        const float4* e4 = reinterpret_cast<const float4*>(emb) + row * 192;
        float ss = 0.f;
#pragma unroll
        for (int k = 0; k < 12; k++) { int i = c16 + 16 * k; float4 v = e4[i]; xr[i] = v; ss += d4(v, v); }
        ss = r16(ss);
        float inv = rsqrtf(ss * (1.f / 768.f) + EPSF);
        if (blockIdx.x == 0) {
#pragma unroll
            for (int k = 0; k < 12; k++) { int i = c16 + 16 * k; hA4[i] = xr[i]; }
        }
        const float4* p4 = reinterpret_cast<const float4*>(pan);
#pragma unroll
        for (int k = 0; k < 12; k++) { int i = c16 + 16 * k; xr[i] = f4nrm(xr[i], inv, p4[i]); }
    } else {
        const float4* f0 = reinterpret_cast<const float4*>(ff) + row * 192;
        const float4* f1 = f0 + TT * 192;
        const float4* f2 = f1 + TT * 192;
        const float4* f3 = f2 + TT * 192;
        float ss = 0.f;
#pragma unroll
        for (int k = 0; k < 12; k++) {
            int i = c16 + 16 * k;
            float4 v = f4add4(f0[i], f1[i], f2[i], f3[i]);
            xr[i] = v; ss += d4(v, v);
        }
        ss = r16(ss);
        float inv = rsqrtf(ss * (1.f / 768.f) + EPSF);
        const float4* hb4 = reinterpret_cast<const float4*>(hB) + row * 192;
        const float4* po4 = reinterpret_cast<const float4*>(pofn_prev);
        float ss2 = 0.f;
#pragma unroll
        for (int k = 0; k < 12; k++) {
            int i = c16 + 16 * k;
            float4 v = f4res(hb4[i], xr[i], inv, po4[i]);
            xr[i] = v; ss2 += d4(v, v);
            if (blockIdx.x == 0) hA4[i] = v;
        }
        ss2 = r16(ss2);
        float inv2 = rsqrtf(ss2 * (1.f / 768.f) + EPSF);
        const float4* p4 = reinterpret_cast<const float4*>(pan);
#pragma unroll
        for (int k = 0; k < 12; k++) { int i = c16 + 16 * k; xr[i] = f4nrm(xr[i], inv2, p4[i]); }
    }
    __syncthreads();
    const int wv = tid >> 6, lane = tid & 63;
    const int o0 = blockIdx.x * 8 + wv;
    const int o1 = o0 + 4;
    float acca[TT], accb[TT];
    gemv_row2<192>(reinterpret_cast<const float4*>(W + (size_t)o0 * DD),
                   reinterpret_cast<const float4*>(W + (size_t)o1 * DD), xs, lane, acca, accb);
    if (lane < TT) {
        qkvo[lane * OQKV + o0] = acca[lane];
        qkvo[lane * OQKV + o1] = accb[lane];
    }
}

// ---------- K2: attention partials, 16 q-rows per block ----------
// grid (65, 2, 4). Scores: lane l16 owns positions i = 16j + l16 outright; fixed-max
// softmax (M0): pe = exp(softcap + mask - M0) computed inline, denominator via r16
// shuffle over lane partials. part[128] = M0 uniformly -> combine weights all 1.
__global__ __launch_bounds__(256) void k_attn(const float* __restrict__ qkv,
                                              const float* __restrict__ kc,  // [2][4096][128]
                                              const float* __restrict__ vc,  // [2][128][4096]
                                              const float* __restrict__ cosp,
                                              const float* __restrict__ sinp,
                                              const float* __restrict__ mask, // [16][4112]
                                              const float* __restrict__ qnw,
                                              const float* __restrict__ knw,
                                              float* __restrict__ part,
                                              float* __restrict__ kout,   // [2][16][128]
                                              float* __restrict__ vout)   // [2][128][16]
{
    __shared__ __align__(16) float kvb[64 * 132];
    __shared__ __align__(16) float qs[16 * 132];
    __shared__ __align__(16) float pls[16 * 68];
    const int tid = threadIdx.x;
    const int c = blockIdx.x;
    const int ng = blockIdx.y;
    const int rq = blockIdx.z;
    const bool newc = (c == 64);

    // --- Q build into qs rows 0..15 (16 rows x 16 threads, 8 dims each)
    {
        int rl = tid >> 4, c16 = tid & 15;
        int r = rq * 16 + rl;
        int tsrc = r >> 2, g = r & 3;
        const float* src = qkv + tsrc * OQKV + ng * 768 + g * 128;
        float ss = 0.f;
#pragma unroll
        for (int j = 0; j < 8; j++) { float v = src[c16 * 8 + j]; ss += v * v; }
        ss = r16(ss);
        float inv = rsqrtf(ss * (1.f / 128.f) + EPSF);
        int pos = r & 15;
        const float* cp = cosp + pos * 128;
        const float* sp = sinp + pos * 128;
#pragma unroll
        for (int j = 0; j < 8; j++) {
            int d = c16 * 8 + j;
            float xn = src[d] * inv * (1.f + qnw[d]);
            float out;
            if (d < 64) { float pr = src[d + 64] * inv * (1.f + qnw[d + 64]); out = xn * cp[d] - pr * sp[d]; }
            else        { float pr = src[d - 64] * inv * (1.f + qnw[d - 64]); out = xn * cp[d] + pr * sp[d]; }
            qs[rl * 132 + d] = out;
        }
    }
    // --- K stage (no dependency on Q build; one sync covers both)
    if (!newc) {
        int rowk = tid >> 2, q4i = tid & 3;
        const float4* k4 = reinterpret_cast<const float4*>(kc + (size_t)(ng * SCCH + c * 64 + rowk) * 128);
#pragma unroll
        for (int k = 0; k < 8; k++) {
            float4 v = k4[q4i * 8 + k];
            *reinterpret_cast<float4*>(&kvb[rowk * 132 + 4 * (q4i * 8 + k)]) = v;
        }
    } else {
        int t = tid >> 4, c16 = tid & 15;
        const float* src = qkv + t * OQKV + ng * 768 + 4 * 128;
        float ss = 0.f;
#pragma unroll
        for (int j = 0; j < 8; j++) { float v = src[c16 * 8 + j]; ss += v * v; }
        ss = r16(ss);
        float inv = rsqrtf(ss * (1.f / 128.f) + EPSF);
        const float* cp = cosp + t * 128;
        const float* sp = sinp + t * 128;
#pragma unroll
        for (int j = 0; j < 8; j++) {
            int d = c16 * 8 + j;
            float xn = src[d] * inv * (1.f + knw[d]);
            float out;
            if (d < 64) { float pr = src[d + 64] * inv * (1.f + knw[d + 64]); out = xn * cp[d] - pr * sp[d]; }
            else        { float pr = src[d - 64] * inv * (1.f + knw[d - 64]); out = xn * cp[d] + pr * sp[d]; }
            kvb[t * 132 + d] = out;
            if (rq == 0) kout[(ng * TT + t) * 128 + d] = out;
        }
        for (int i = tid; i < 48 * 132; i += 256) kvb[16 * 132 + i] = 0.f;
    }
    __syncthreads();
    // --- scores: lane (rr, l16) computes full dot, applies softcap+mask, exp(.-M0)
    const int rr = tid >> 4;
    const int l16 = tid & 15;
    const int r = rq * 16 + rr;
    const int pos = r & 15;
    const int cnt_pos = newc ? TT : 64;
    const float* mrow = mask + pos * STOT + c * 64;
    const float4* qrow = reinterpret_cast<const float4*>(qs + rr * 132);
    float* prow = pls + rr * 68;
    float lsl = 0.f;
#pragma unroll 2
    for (int j = 0; j < 4; j++) {
        int i = 16 * j + l16;
        const float4* krow = reinterpret_cast<const float4*>(kvb + i * 132);
        float p = 0.f;
#pragma unroll 4
        for (int w = 0; w < 32; w++) p += d4(qrow[w], krow[w]);
        float pe;
        if (i < cnt_pos) {
            p *= SCALEQ;
            p = 50.f * ftanh(p * 0.02f);
            pe = __expf(p + mrow[i] - M0);
        } else {
            pe = 0.f;
        }
        prow[i] = pe;   // owner-private slot
        lsl += pe;
    }
    // denominator via shuffle over the 16-lane row group; m is the constant M0
    {
        float lsum = r16(lsl);
        if (l16 == 0) {
            float* pb = part + (size_t)((ng * NCH + c) * 64 + r) * 132;
            pb[128] = M0; pb[129] = lsum;
        }
    }
    __syncthreads();
    // --- V stage (reuse kvb) -> [pos][dim]
    if (!newc) {
        int d = tid >> 1, hv = tid & 1;
        const float4* v4 = reinterpret_cast<const float4*>(vc + (size_t)(ng * 128 + d) * SCCH + c * 64);
#pragma unroll
        for (int k = 0; k < 8; k++) {
            float4 v = v4[hv * 8 + k];
            int sl = hv * 32 + 4 * k;
            kvb[(sl + 0) * 132 + d] = v.x;
            kvb[(sl + 1) * 132 + d] = v.y;
            kvb[(sl + 2) * 132 + d] = v.z;
            kvb[(sl + 3) * 132 + d] = v.w;
        }
    } else {
        int t = tid >> 4, c16 = tid & 15;
        const float* src = qkv + t * OQKV + ng * 768 + 5 * 128;
#pragma unroll
        for (int j = 0; j < 8; j++) {
            int d = c16 * 8 + j;
            float v = src[d];
            kvb[t * 132 + d] = v;
            if (rq == 0) vout[(ng * 128 + d) * TT + t] = v;
        }
    }
    __syncthreads();
    // --- PV (octet structure: dims dq*4+32m, positions split by half; merge via shfl_xor(8))
    const int half = (tid >> 3) & 1;
    const int dq = tid & 7;
    float4 accv[4];
#pragma unroll
    for (int m2 = 0; m2 < 4; m2++) accv[m2] = make_float4(0.f, 0.f, 0.f, 0.f);
#pragma unroll 4
    for (int jj = 0; jj < 32; jj++) {
        int i = half * 32 + jj;
        float p = prow[i];
        const float4* v4 = reinterpret_cast<const float4*>(kvb + i * 132);
        accv[0] = fma4(p, v4[dq], accv[0]);
        accv[1] = fma4(p, v4[dq + 8], accv[1]);
        accv[2] = fma4(p, v4[dq + 16], accv[2]);
        accv[3] = fma4(p, v4[dq + 24], accv[3]);
    }
#pragma unroll
    for (int m2 = 0; m2 < 4; m2++) {
        accv[m2].x += __shfl_xor(accv[m2].x, 8);
        accv[m2].y += __shfl_xor(accv[m2].y, 8);
        accv[m2].z += __shfl_xor(accv[m2].z, 8);
        accv[m2].w += __shfl_xor(accv[m2].w, 8);
    }
    if (half == 0) {
        float* pb = part + (size_t)((ng * NCH + c) * 64 + r) * 132;
        float4* pb4 = reinterpret_cast<float4*>(pb);
        pb4[dq] = accv[0]; pb4[dq + 8] = accv[1]; pb4[dq + 16] = accv[2]; pb4[dq + 24] = accv[3];
    }
}

// ---------- K3: combine partials -> attn [t][h*128+d] (unchanged; M uniform) ----------
__global__ __launch_bounds__(128) void k_combine(const float* __restrict__ part,
                                                 float* __restrict__ attn) {
    __shared__ float marr[NCH], larr[NCH], warr[NCH];
    __shared__ __align__(16) float mrg[4][128];
    int blk = blockIdx.x;
    int ng = blk >> 6, r = blk & 63;
    int tid = threadIdx.x;
    const float* pb = part + (size_t)(ng * NCH * 64 + r) * 132;
    if (tid < NCH) {
        marr[tid] = pb[(size_t)tid * 64 * 132 + 128];
        larr[tid] = pb[(size_t)tid * 64 * 132 + 129];
    }
    __syncthreads();
    float M = -1e30f;
#pragma unroll 4
    for (int cc = 0; cc < NCH; cc++) M = fmaxf(M, marr[cc]);
    if (tid < NCH) warr[tid] = __expf(marr[tid] - M);
    __syncthreads();
    float Lsum = 0.f;
#pragma unroll 4
    for (int cc = 0; cc < NCH; cc++) Lsum = fmaf(larr[cc], warr[cc], Lsum);
    int q = tid >> 5, dd = tid & 31;
    float4 A4 = make_float4(0.f, 0.f, 0.f, 0.f);
    for (int cc = q; cc < NCH; cc += 4) {
        const float4* pa = reinterpret_cast<const float4*>(pb + (size_t)cc * 64 * 132);
        A4 = fma4(warr[cc], pa[dd], A4);
    }
    *reinterpret_cast<float4*>(&mrg[q][dd * 4]) = A4;
    __syncthreads();
    int d = tid;
    float A = (mrg[0][d] + mrg[1][d]) + (mrg[2][d] + mrg[3][d]);
    int h = ng * 4 + (r >> 4), pos = r & 15;
    attn[pos * 1024 + h * 128 + d] = A / Lsum;
}

// ---------- K4: out projection (pairwise) ----------
__global__ __launch_bounds__(256) void k_outproj(const float* __restrict__ W, // [768][1024]
                                                 const float* __restrict__ attn,
                                                 float* __restrict__ y) {
    int tid = threadIdx.x;
    int wv = tid >> 6, lane = tid & 63;
    int o0 = blockIdx.x * 8 + wv;
    int o1 = o0 + 4;
    float acca[TT], accb[TT];
    gemv_row2<256>(reinterpret_cast<const float4*>(W + (size_t)o0 * 1024),
                   reinterpret_cast<const float4*>(W + (size_t)o1 * 1024), attn, lane, acca, accb);
    if (lane < TT) {
        y[lane * DD + o0] = acca[lane];
        y[lane * DD + o1] = accb[lane];
    }
}

// ---------- K5: post-attn residual+norm, pre-ff norm, gate/up GEMV4 + GELU*up ----------
// grid 384, 8 f-rows/block.
__global__ __launch_bounds__(256) void k_gateup(const float* __restrict__ hA,
                                                const float* __restrict__ y,
                                                const float* __restrict__ postw,
                                                const float* __restrict__ pfn,
                                                const float* __restrict__ gw,
                                                const float* __restrict__ uw,
                                                float* __restrict__ act,
                                                float* __restrict__ hB) {
    __shared__ __align__(16) float xs[TT * DD];
    int tid = threadIdx.x;
    int row = tid >> 4, c16 = tid & 15;
    float4* xr = reinterpret_cast<float4*>(xs) + row * 192;
    const float4* y4 = reinterpret_cast<const float4*>(y) + row * 192;
    float ss = 0.f;
#pragma unroll
    for (int k = 0; k < 12; k++) { int i = c16 + 16 * k; float4 v = y4[i]; xr[i] = v; ss += d4(v, v); }
    ss = r16(ss);
    float inv = rsqrtf(ss * (1.f / 768.f) + EPSF);
    const float4* ha4 = reinterpret_cast<const float4*>(hA) + row * 192;
    const float4* pw4 = reinterpret_cast<const float4*>(postw);
    float4* hB4 = reinterpret_cast<float4*>(hB) + row * 192;
    float ss2 = 0.f;
#pragma unroll
    for (int k = 0; k < 12; k++) {
        int i = c16 + 16 * k;
        float4 v = f4res(ha4[i], xr[i], inv, pw4[i]);
        xr[i] = v; ss2 += d4(v, v);
        if (blockIdx.x == 0) hB4[i] = v;
    }
    ss2 = r16(ss2);
    float inv2 = rsqrtf(ss2 * (1.f / 768.f) + EPSF);
    const float4* pf4 = reinterpret_cast<const float4*>(pfn);
#pragma unroll
    for (int k = 0; k < 12; k++) { int i = c16 + 16 * k; xr[i] = f4nrm(xr[i], inv2, pf4[i]); }
    __syncthreads();
    int wv = tid >> 6, lane = tid & 63;
    int f0 = blockIdx.x * 8 + wv;
    int f1 = f0 + 4;
    float ag0[TT], ag1[TT], au0[TT], au1[TT];
    gemv_row4<192>(reinterpret_cast<const float4*>(gw + (size_t)f0 * DD),
                   reinterpret_cast<const float4*>(gw + (size_t)f1 * DD),
                   reinterpret_cast<const float4*>(uw + (size_t)f0 * DD),
                   reinterpret_cast<const float4*>(uw + (size_t)f1 * DD),
                   xs, lane, ag0, ag1, au0, au1);
    if (lane < TT) {
        {
            float g = ag0[lane], u = au0[lane];
            float inner = 0.7978845608028654f * fmaf(0.044715f * g, g * g, g);
            act[lane * FFF + f0] = 0.5f * g * (1.f + ftanh(inner)) * u;
        }
        {
            float g = ag1[lane], u = au1[lane];
            float inner = 0.7978845608028654f * fmaf(0.044715f * g, g * g, g);
            act[lane * FFF + f1] = 0.5f * g * (1.f + ftanh(inner)) * u;
        }
    }
}

// ---------- K6: down GEMV in f-quarters -> ff partials [4][16][768] ----------
// grid 384: fq = blk&3, dc = blk>>2 (0..95) x 8 rows (pairwise).
__global__ __launch_bounds__(256) void k_down(const float* __restrict__ W, // [768][3072]
                                              const float* __restrict__ act,
                                              float* __restrict__ ffp) {
    __shared__ __align__(16) float xs[TT * DD];
    int tid = threadIdx.x;
    int fq = blockIdx.x & 3, dc = blockIdx.x >> 2;
    {
        const float4* a4 = reinterpret_cast<const float4*>(act);
        float4* s4 = reinterpret_cast<float4*>(xs);
#pragma unroll
        for (int k = 0; k < 12; k++) {
            int i = tid + 256 * k;
            int t = i / 192, cq = i - t * 192;
            s4[i] = a4[t * 768 + fq * 192 + cq];
        }
    }
    __syncthreads();
    int wv = tid >> 6, lane = tid & 63;
    int o0 = dc * 8 + wv;
    int o1 = o0 + 4;
    float acca[TT], accb[TT];
    gemv_row2<192>(reinterpret_cast<const float4*>(W + (size_t)o0 * FFF + fq * 768),
                   reinterpret_cast<const float4*>(W + (size_t)o1 * FFF + fq * 768), xs, lane, acca, accb);
    if (lane < TT) {
        ffp[(fq * TT + lane) * DD + o0] = acca[lane];
        ffp[(fq * TT + lane) * DD + o1] = accb[lane];
    }
}

// ---------- lm_head with fused final-x (quad rows) ----------
// grid 500, 64 rows/block: 4 quads per wave.
__global__ __launch_bounds__(256) void k_lmfused(const float* __restrict__ hB,
                                                 const float* __restrict__ ff,    // [4][16][768]
                                                 const float* __restrict__ pofn25,
                                                 const float* __restrict__ fnw,
                                                 const float* __restrict__ W,     // [32000][768]
                                                 float* __restrict__ logits) {
    __shared__ __align__(16) float xs[TT * DD];
    int tid = threadIdx.x;
    int row = tid >> 4, c16 = tid & 15;
    float4* xr = reinterpret_cast<float4*>(xs) + row * 192;
    const float4* f0 = reinterpret_cast<const float4*>(ff) + row * 192;
    const float4* f1 = f0 + TT * 192;
    const float4* f2 = f1 + TT * 192;
    const float4* f3 = f2 + TT * 192;
    float ss = 0.f;
#pragma unroll
    for (int k = 0; k < 12; k++) {
        int i = c16 + 16 * k;
        float4 v = f4add4(f0[i], f1[i], f2[i], f3[i]);
        xr[i] = v; ss += d4(v, v);
    }
    ss = r16(ss);
    float inv = rsqrtf(ss * (1.f / 768.f) + EPSF);
    const float4* hb4 = reinterpret_cast<const float4*>(hB) + row * 192;
    const float4* po4 = reinterpret_cast<const float4*>(pofn25);
    float ss2 = 0.f;
#pragma unroll
    for (int k = 0; k < 12; k++) {
        int i = c16 + 16 * k;
        float4 v = f4res(hb4[i], xr[i], inv, po4[i]);
        xr[i] = v; ss2 += d4(v, v);
    }
    ss2 = r16(ss2);
    float inv2 = rsqrtf(ss2 * (1.f / 768.f) + EPSF);
    const float4* fn4 = reinterpret_cast<const float4*>(fnw);
#pragma unroll
    for (int k = 0; k < 12; k++) { int i = c16 + 16 * k; xr[i] = f4nrm(xr[i], inv2, fn4[i]); }
    __syncthreads();
    int wv = tid >> 6, lane = tid & 63;
#pragma unroll
    for (int rr = 0; rr < 4; ++rr) {
        int o0 = blockIdx.x * 64 + rr * 16 + wv;
        int o1 = o0 + 4;
        int o2 = o0 + 8;
        int o3 = o0 + 12;
        float acca[TT], accb[TT], accc[TT], accd[TT];
        gemv_row4<192>(reinterpret_cast<const float4*>(W + (size_t)o0 * DD),
                       reinterpret_cast<const float4*>(W + (size_t)o1 * DD),
                       reinterpret_cast<const float4*>(W + (size_t)o2 * DD),
                       reinterpret_cast<const float4*>(W + (size_t)o3 * DD),
                       xs, lane, acca, accb, accc, accd);
        if (lane < TT) {
            logits[lane * VV + o0] = acca[lane];
            logits[lane * VV + o1] = accb[lane];
            logits[lane * VV + o2] = accc[lane];
            logits[lane * VV + o3] = accd[lane];
        }
    }
}

extern "C" void kernel_launch(void* const* d_in, const int* in_sizes, int n_in,
                              void* d_out, int out_size, void* d_ws, size_t ws_size,
                              hipStream_t stream) {
    const float* emb   = (const float*)d_in[0];
    const float* maskg = (const float*)d_in[1];
    const float* maskl = (const float*)d_in[2];
    const float* cosg  = (const float*)d_in[3];
    const float* sing  = (const float*)d_in[4];
    const float* cosl  = (const float*)d_in[5];
    const float* sinl  = (const float*)d_in[6];
    const float* kck   = (const float*)d_in[7];
    const float* kcv   = (const float*)d_in[8];
    const float* pan   = (const float*)d_in[9];
    const float* qkvw  = (const float*)d_in[10];
    const float* qnw   = (const float*)d_in[11];
    const float* knw   = (const float*)d_in[12];
    const float* outw  = (const float*)d_in[13];
    const float* postw = (const float*)d_in[14];
    const float* pfnw  = (const float*)d_in[15];
    const float* gw    = (const float*)d_in[16];
    const float* uw    = (const float*)d_in[17];
    const float* dw    = (const float*)d_in[18];
    const float* pofn  = (const float*)d_in[19];
    const float* fnw   = (const float*)d_in[20];
    const float* lmw   = (const float*)d_in[21];

    float* ws   = (float*)d_ws;
    float* hA   = ws;                 // 12288
    float* hB   = hA + 12288;         // 12288
    float* qkvb = hB + 12288;         // 24576
    float* attnb = qkvb + 24576;      // 16384
    float* yb   = attnb + 16384;      // 12288
    float* act  = yb + 12288;         // 49152
    float* ffp  = act + 49152;        // 49152
    float* part = ffp + 49152;        // 2*65*64*132 = 1,098,240

    float* outp = (float*)d_out;
    float* outK = outp + 512000;
    float* outV = outK + 106496;

    for (int l = 0; l < NL; l++) {
        int loc = ((l + 1) % 6) == 0;
        const float* cosp = loc ? cosl : cosg;
        const float* sinp = loc ? sinl : sing;
        const float* maskp = loc ? maskl : maskg;
        k_qkv<<<192, 256, 0, stream>>>(l == 0 ? 1 : 0, hB, ffp, emb,
                                       l ? (pofn + (size_t)(l - 1) * DD) : pofn,
                                       pan + (size_t)l * DD,
                                       qkvw + (size_t)l * OQKV * DD, qkvb, hA);
        k_attn<<<dim3(NCH, 2, 4), 256, 0, stream>>>(qkvb,
                                                    kck + (size_t)l * 2 * SCCH * HDD,
                                                    kcv + (size_t)l * 2 * HDD * SCCH,
                                                    cosp, sinp, maskp,
                                                    qnw + (size_t)l * HDD, knw + (size_t)l * HDD,
                                                    part,
                                                    outK + (size_t)l * 2 * TT * HDD,
                                                    outV + (size_t)l * 2 * HDD * TT);
        k_combine<<<128, 128, 0, stream>>>(part, attnb);
        k_outproj<<<96, 256, 0, stream>>>(outw + (size_t)l * DD * 1024, attnb, yb);
        k_gateup<<<384, 256, 0, stream>>>(hA, yb, postw + (size_t)l * DD, pfnw + (size_t)l * DD,
                                          gw + (size_t)l * FFF * DD, uw + (size_t)l * FFF * DD,
                                          act, hB);
        k_down<<<384, 256, 0, stream>>>(dw + (size_t)l * DD * FFF, act, ffp);
    }
    k_lmfused<<<500, 256, 0, stream>>>(hB, ffp, pofn + (size_t)25 * DD, fnw, lmw, outp);
}

// Round 21
// 2513.030 us; speedup vs baseline: 1.1998x; 1.0318x over previous
//
#include <hip/hip_runtime.h>
#include <hip/hip_bf16.h>
#include <math.h>

// ---- problem constants ----
#define NL 26
#define TT 16
#define DD 768
#define HDD 128
#define FFF 3072
#define VV 32000
#define SCCH 4096
#define STOT 4112      // SC + T
#define OQKV 1536      // NG*(G+2)*HD
#define EPSF 1e-6f
#define SCALEQ 0.08838834764831845f  // 1/sqrt(128)
#define NCH 65         // 64 cache chunks of 64 + 1 new-token chunk
#define M0 12.0f       // fixed softmax max: |softcap| <= 11.8 (normed q,k), masks <= 0

// native vector type for nontemporal builtins
typedef float nfloat4 __attribute__((ext_vector_type(4)));

// ---------- helpers ----------
__device__ __forceinline__ float d4(const float4 a, const float4 b) {
    return fmaf(a.x, b.x, fmaf(a.y, b.y, fmaf(a.z, b.z, a.w * b.w)));
}
__device__ __forceinline__ float4 fma4(float p, const float4 v, float4 a) {
    return make_float4(fmaf(p, v.x, a.x), fmaf(p, v.y, a.y),
                       fmaf(p, v.z, a.z), fmaf(p, v.w, a.w));
}
__device__ __forceinline__ float4 f4acc(const float4 v, float4 a) {
    return make_float4(v.x + a.x, v.y + a.y, v.z + a.z, v.w + a.w);
}
__device__ __forceinline__ float4 f4add4(float4 a, float4 b, float4 c, float4 d) {
    return make_float4((a.x + b.x) + (c.x + d.x), (a.y + b.y) + (c.y + d.y),
                       (a.z + b.z) + (c.z + d.z), (a.w + b.w) + (c.w + d.w));
}
// h + f*s*(1+w)
__device__ __forceinline__ float4 f4res(float4 h, float4 f, float s, float4 w) {
    return make_float4(fmaf(f.x * s, 1.f + w.x, h.x), fmaf(f.y * s, 1.f + w.y, h.y),
                       fmaf(f.z * s, 1.f + w.z, h.z), fmaf(f.w * s, 1.f + w.w, h.w));
}
// h*s*(1+w)
__device__ __forceinline__ float4 f4nrm(float4 h, float s, float4 w) {
    return make_float4(h.x * s * (1.f + w.x), h.y * s * (1.f + w.y),
                       h.z * s * (1.f + w.z), h.w * s * (1.f + w.w));
}
__device__ __forceinline__ float r16(float v) {
    v += __shfl_xor(v, 1); v += __shfl_xor(v, 2); v += __shfl_xor(v, 4); v += __shfl_xor(v, 8);
    return v;
}
__device__ __forceinline__ float rwave(float v) {
    v += __shfl_xor(v, 32); v += __shfl_xor(v, 16); v += __shfl_xor(v, 8);
    v += __shfl_xor(v, 4);  v += __shfl_xor(v, 2);  v += __shfl_xor(v, 1);
    return v;
}
// fast tanh: saturation-safe rational form (rel err ~1e-7)
__device__ __forceinline__ float ftanh(float x) {
    float t = __expf(-2.f * fabsf(x));
    float th = (1.f - t) / (1.f + t);
    return copysignf(th, x);
}
// non-temporal float4 load (weights are single-use streams; keep L2 for hot data)
__device__ __forceinline__ float4 ldnt4(const float4* __restrict__ p) {
    nfloat4 v = __builtin_nontemporal_load(reinterpret_cast<const nfloat4*>(p));
    return make_float4(v.x, v.y, v.z, v.w);
}

// GEMV inner, 2 rows interleaved (NT weight loads).
template <int K4>
__device__ __forceinline__ void gemv_row2(const float4* __restrict__ wa,
                                          const float4* __restrict__ wb,
                                          const float* __restrict__ xs, int lane,
                                          float* __restrict__ acca,
                                          float* __restrict__ accb) {
#pragma unroll
    for (int t = 0; t < TT; t++) { acca[t] = 0.f; accb[t] = 0.f; }
    const float4* x4 = reinterpret_cast<const float4*>(xs);
#pragma unroll
    for (int it = 0; it < K4 / 64; ++it) {
        float4 a = ldnt4(&wa[it * 64 + lane]);
        float4 b = ldnt4(&wb[it * 64 + lane]);
#pragma unroll
        for (int t = 0; t < TT; t++) {
            float4 x = x4[t * K4 + it * 64 + lane];
            acca[t] = fmaf(a.x, x.x, fmaf(a.y, x.y, fmaf(a.z, x.z, fmaf(a.w, x.w, acca[t]))));
            accb[t] = fmaf(b.x, x.x, fmaf(b.y, x.y, fmaf(b.z, x.z, fmaf(b.w, x.w, accb[t]))));
        }
    }
#pragma unroll
    for (int t = 0; t < TT; t++) { acca[t] = rwave(acca[t]); accb[t] = rwave(accb[t]); }
}

// GEMV inner, 4 rows interleaved (one shared x pass, NT weight loads).
template <int K4>
__device__ __forceinline__ void gemv_row4(const float4* __restrict__ wa,
                                          const float4* __restrict__ wb,
                                          const float4* __restrict__ wc,
                                          const float4* __restrict__ wd,
                                          const float* __restrict__ xs, int lane,
                                          float* __restrict__ acca, float* __restrict__ accb,
                                          float* __restrict__ accc, float* __restrict__ accd) {
#pragma unroll
    for (int t = 0; t < TT; t++) { acca[t] = 0.f; accb[t] = 0.f; accc[t] = 0.f; accd[t] = 0.f; }
    const float4* x4 = reinterpret_cast<const float4*>(xs);
#pragma unroll
    for (int it = 0; it < K4 / 64; ++it) {
        float4 a = ldnt4(&wa[it * 64 + lane]);
        float4 b = ldnt4(&wb[it * 64 + lane]);
        float4 c = ldnt4(&wc[it * 64 + lane]);
        float4 d = ldnt4(&wd[it * 64 + lane]);
#pragma unroll
        for (int t = 0; t < TT; t++) {
            float4 x = x4[t * K4 + it * 64 + lane];
            acca[t] = fmaf(a.x, x.x, fmaf(a.y, x.y, fmaf(a.z, x.z, fmaf(a.w, x.w, acca[t]))));
            accb[t] = fmaf(b.x, x.x, fmaf(b.y, x.y, fmaf(b.z, x.z, fmaf(b.w, x.w, accb[t]))));
            accc[t] = fmaf(c.x, x.x, fmaf(c.y, x.y, fmaf(c.z, x.z, fmaf(c.w, x.w, accc[t]))));
            accd[t] = fmaf(d.x, x.x, fmaf(d.y, x.y, fmaf(d.z, x.z, fmaf(d.w, x.w, accd[t]))));
        }
    }
#pragma unroll
    for (int t = 0; t < TT; t++) {
        acca[t] = rwave(acca[t]); accb[t] = rwave(accb[t]);
        accc[t] = rwave(accc[t]); accd[t] = rwave(accd[t]);
    }
}

// ---------- K1: (deferred ff residual) + pre-attn rmsnorm + QKV GEMV ----------
// grid 192, 8 rows/block: wave wv owns pair (blk*8+wv, blk*8+wv+4).
__global__ __launch_bounds__(256) void k_qkv(const int first,
                                             const float* __restrict__ hB,
                                             const float* __restrict__ ff,   // [4][16][768]
                                             const float* __restrict__ emb,
                                             const float* __restrict__ pofn_prev,
                                             const float* __restrict__ pan,
                                             const float* __restrict__ W,    // [1536][768]
                                             float* __restrict__ qkvo,       // [16][1536]
                                             float* __restrict__ hA) {
    __shared__ __align__(16) float xs[TT * DD];
    const int tid = threadIdx.x;
    const int row = tid >> 4, c16 = tid & 15;
    float4* xr = reinterpret_cast<float4*>(xs) + row * 192;
    float4* hA4 = reinterpret_cast<float4*>(hA) + row * 192;
    if (first) {
        const float4* e4 = reinterpret_cast<const float4*>(emb) + row * 192;
        float ss = 0.f;
#pragma unroll
        for (int k = 0; k < 12; k++) { int i = c16 + 16 * k; float4 v = e4[i]; xr[i] = v; ss += d4(v, v); }
        ss = r16(ss);
        float inv = rsqrtf(ss * (1.f / 768.f) + EPSF);
        if (blockIdx.x == 0) {
#pragma unroll
            for (int k = 0; k < 12; k++) { int i = c16 + 16 * k; hA4[i] = xr[i]; }
        }
        const float4* p4 = reinterpret_cast<const float4*>(pan);
#pragma unroll
        for (int k = 0; k < 12; k++) { int i = c16 + 16 * k; xr[i] = f4nrm(xr[i], inv, p4[i]); }
    } else {
        const float4* f0 = reinterpret_cast<const float4*>(ff) + row * 192;
        const float4* f1 = f0 + TT * 192;
        const float4* f2 = f1 + TT * 192;
        const float4* f3 = f2 + TT * 192;
        float ss = 0.f;
#pragma unroll
        for (int k = 0; k < 12; k++) {
            int i = c16 + 16 * k;
            float4 v = f4add4(f0[i], f1[i], f2[i], f3[i]);
            xr[i] = v; ss += d4(v, v);
        }
        ss = r16(ss);
        float inv = rsqrtf(ss * (1.f / 768.f) + EPSF);
        const float4* hb4 = reinterpret_cast<const float4*>(hB) + row * 192;
        const float4* po4 = reinterpret_cast<const float4*>(pofn_prev);
        float ss2 = 0.f;
#pragma unroll
        for (int k = 0; k < 12; k++) {
            int i = c16 + 16 * k;
            float4 v = f4res(hb4[i], xr[i], inv, po4[i]);
            xr[i] = v; ss2 += d4(v, v);
            if (blockIdx.x == 0) hA4[i] = v;
        }
        ss2 = r16(ss2);
        float inv2 = rsqrtf(ss2 * (1.f / 768.f) + EPSF);
        const float4* p4 = reinterpret_cast<const float4*>(pan);
#pragma unroll
        for (int k = 0; k < 12; k++) { int i = c16 + 16 * k; xr[i] = f4nrm(xr[i], inv2, p4[i]); }
    }
    __syncthreads();
    const int wv = tid >> 6, lane = tid & 63;
    const int o0 = blockIdx.x * 8 + wv;
    const int o1 = o0 + 4;
    float acca[TT], accb[TT];
    gemv_row2<192>(reinterpret_cast<const float4*>(W + (size_t)o0 * DD),
                   reinterpret_cast<const float4*>(W + (size_t)o1 * DD), xs, lane, acca, accb);
    if (lane < TT) {
        qkvo[lane * OQKV + o0] = acca[lane];
        qkvo[lane * OQKV + o1] = accb[lane];
    }
}

// ---------- K2: attention partials, 16 q-rows per block ----------
// grid (65, 2, 4). Scores: lane l16 owns positions i = 16j + l16 outright; fixed-max
// softmax (M0): pe = exp(softcap + mask - M0) computed inline, denominator via r16
// shuffle. Combine weights are all 1 -> no max slot written.
__global__ __launch_bounds__(256) void k_attn(const float* __restrict__ qkv,
                                              const float* __restrict__ kc,  // [2][4096][128]
                                              const float* __restrict__ vc,  // [2][128][4096]
                                              const float* __restrict__ cosp,
                                              const float* __restrict__ sinp,
                                              const float* __restrict__ mask, // [16][4112]
                                              const float* __restrict__ qnw,
                                              const float* __restrict__ knw,
                                              float* __restrict__ part,
                                              float* __restrict__ kout,   // [2][16][128]
                                              float* __restrict__ vout)   // [2][128][16]
{
    __shared__ __align__(16) float kvb[64 * 132];
    __shared__ __align__(16) float qs[16 * 132];
    __shared__ __align__(16) float pls[16 * 68];
    const int tid = threadIdx.x;
    const int c = blockIdx.x;
    const int ng = blockIdx.y;
    const int rq = blockIdx.z;
    const bool newc = (c == 64);

    // --- Q build into qs rows 0..15 (16 rows x 16 threads, 8 dims each)
    {
        int rl = tid >> 4, c16 = tid & 15;
        int r = rq * 16 + rl;
        int tsrc = r >> 2, g = r & 3;
        const float* src = qkv + tsrc * OQKV + ng * 768 + g * 128;
        float ss = 0.f;
#pragma unroll
        for (int j = 0; j < 8; j++) { float v = src[c16 * 8 + j]; ss += v * v; }
        ss = r16(ss);
        float inv = rsqrtf(ss * (1.f / 128.f) + EPSF);
        int pos = r & 15;
        const float* cp = cosp + pos * 128;
        const float* sp = sinp + pos * 128;
#pragma unroll
        for (int j = 0; j < 8; j++) {
            int d = c16 * 8 + j;
            float xn = src[d] * inv * (1.f + qnw[d]);
            float out;
            if (d < 64) { float pr = src[d + 64] * inv * (1.f + qnw[d + 64]); out = xn * cp[d] - pr * sp[d]; }
            else        { float pr = src[d - 64] * inv * (1.f + qnw[d - 64]); out = xn * cp[d] + pr * sp[d]; }
            qs[rl * 132 + d] = out;
        }
    }
    // --- K stage (no dependency on Q build; one sync covers both)
    if (!newc) {
        int rowk = tid >> 2, q4i = tid & 3;
        const float4* k4 = reinterpret_cast<const float4*>(kc + (size_t)(ng * SCCH + c * 64 + rowk) * 128);
#pragma unroll
        for (int k = 0; k < 8; k++) {
            float4 v = k4[q4i * 8 + k];
            *reinterpret_cast<float4*>(&kvb[rowk * 132 + 4 * (q4i * 8 + k)]) = v;
        }
    } else {
        int t = tid >> 4, c16 = tid & 15;
        const float* src = qkv + t * OQKV + ng * 768 + 4 * 128;
        float ss = 0.f;
#pragma unroll
        for (int j = 0; j < 8; j++) { float v = src[c16 * 8 + j]; ss += v * v; }
        ss = r16(ss);
        float inv = rsqrtf(ss * (1.f / 128.f) + EPSF);
        const float* cp = cosp + t * 128;
        const float* sp = sinp + t * 128;
#pragma unroll
        for (int j = 0; j < 8; j++) {
            int d = c16 * 8 + j;
            float xn = src[d] * inv * (1.f + knw[d]);
            float out;
            if (d < 64) { float pr = src[d + 64] * inv * (1.f + knw[d + 64]); out = xn * cp[d] - pr * sp[d]; }
            else        { float pr = src[d - 64] * inv * (1.f + knw[d - 64]); out = xn * cp[d] + pr * sp[d]; }
            kvb[t * 132 + d] = out;
            if (rq == 0) kout[(ng * TT + t) * 128 + d] = out;
        }
        for (int i = tid; i < 48 * 132; i += 256) kvb[16 * 132 + i] = 0.f;
    }
    __syncthreads();
    // --- scores: lane (rr, l16) computes full dot, applies softcap+mask, exp(.-M0)
    const int rr = tid >> 4;
    const int l16 = tid & 15;
    const int r = rq * 16 + rr;
    const int pos = r & 15;
    const int cnt_pos = newc ? TT : 64;
    const float* mrow = mask + pos * STOT + c * 64;
    const float4* qrow = reinterpret_cast<const float4*>(qs + rr * 132);
    float* prow = pls + rr * 68;
    float lsl = 0.f;
#pragma unroll 2
    for (int j = 0; j < 4; j++) {
        int i = 16 * j + l16;
        const float4* krow = reinterpret_cast<const float4*>(kvb + i * 132);
        float p = 0.f;
#pragma unroll 4
        for (int w = 0; w < 32; w++) p += d4(qrow[w], krow[w]);
        float pe;
        if (i < cnt_pos) {
            p *= SCALEQ;
            p = 50.f * ftanh(p * 0.02f);
            pe = __expf(p + mrow[i] - M0);
        } else {
            pe = 0.f;
        }
        prow[i] = pe;   // owner-private slot
        lsl += pe;
    }
    // denominator via shuffle over the 16-lane row group (max is constant M0)
    {
        float lsum = r16(lsl);
        if (l16 == 0) {
            float* pb = part + (size_t)((ng * NCH + c) * 64 + r) * 132;
            pb[129] = lsum;
        }
    }
    __syncthreads();
    // --- V stage (reuse kvb) -> [pos][dim]
    if (!newc) {
        int d = tid >> 1, hv = tid & 1;
        const float4* v4 = reinterpret_cast<const float4*>(vc + (size_t)(ng * 128 + d) * SCCH + c * 64);
#pragma unroll
        for (int k = 0; k < 8; k++) {
            float4 v = v4[hv * 8 + k];
            int sl = hv * 32 + 4 * k;
            kvb[(sl + 0) * 132 + d] = v.x;
            kvb[(sl + 1) * 132 + d] = v.y;
            kvb[(sl + 2) * 132 + d] = v.z;
            kvb[(sl + 3) * 132 + d] = v.w;
        }
    } else {
        int t = tid >> 4, c16 = tid & 15;
        const float* src = qkv + t * OQKV + ng * 768 + 5 * 128;
#pragma unroll
        for (int j = 0; j < 8; j++) {
            int d = c16 * 8 + j;
            float v = src[d];
            kvb[t * 132 + d] = v;
            if (rq == 0) vout[(ng * 128 + d) * TT + t] = v;
        }
    }
    __syncthreads();
    // --- PV (octet structure: dims dq*4+32m, positions split by half; merge via shfl_xor(8))
    const int half = (tid >> 3) & 1;
    const int dq = tid & 7;
    float4 accv[4];
#pragma unroll
    for (int m2 = 0; m2 < 4; m2++) accv[m2] = make_float4(0.f, 0.f, 0.f, 0.f);
#pragma unroll 4
    for (int jj = 0; jj < 32; jj++) {
        int i = half * 32 + jj;
        float p = prow[i];
        const float4* v4 = reinterpret_cast<const float4*>(kvb + i * 132);
        accv[0] = fma4(p, v4[dq], accv[0]);
        accv[1] = fma4(p, v4[dq + 8], accv[1]);
        accv[2] = fma4(p, v4[dq + 16], accv[2]);
        accv[3] = fma4(p, v4[dq + 24], accv[3]);
    }
#pragma unroll
    for (int m2 = 0; m2 < 4; m2++) {
        accv[m2].x += __shfl_xor(accv[m2].x, 8);
        accv[m2].y += __shfl_xor(accv[m2].y, 8);
        accv[m2].z += __shfl_xor(accv[m2].z, 8);
        accv[m2].w += __shfl_xor(accv[m2].w, 8);
    }
    if (half == 0) {
        float* pb = part + (size_t)((ng * NCH + c) * 64 + r) * 132;
        float4* pb4 = reinterpret_cast<float4*>(pb);
        pb4[dq] = accv[0]; pb4[dq + 8] = accv[1]; pb4[dq + 16] = accv[2]; pb4[dq + 24] = accv[3];
    }
}

// ---------- K3: combine partials (all weights 1) -> attn [t][h*128+d] ----------
// Pure sum over chunks: Lsum = sum larr; A = sum of PV partials. No max/exp passes.
__global__ __launch_bounds__(128) void k_combine(const float* __restrict__ part,
                                                 float* __restrict__ attn) {
    __shared__ float larr[NCH];
    __shared__ __align__(16) float mrg[4][128];
    int blk = blockIdx.x;
    int ng = blk >> 6, r = blk & 63;
    int tid = threadIdx.x;
    const float* pb = part + (size_t)(ng * NCH * 64 + r) * 132;
    if (tid < NCH) larr[tid] = pb[(size_t)tid * 64 * 132 + 129];
    __syncthreads();
    float Lsum = 0.f;
#pragma unroll 4
    for (int cc = 0; cc < NCH; cc++) Lsum += larr[cc];
    int q = tid >> 5, dd = tid & 31;
    float4 A4 = make_float4(0.f, 0.f, 0.f, 0.f);
    for (int cc = q; cc < NCH; cc += 4) {
        const float4* pa = reinterpret_cast<const float4*>(pb + (size_t)cc * 64 * 132);
        A4 = f4acc(pa[dd], A4);
    }
    *reinterpret_cast<float4*>(&mrg[q][dd * 4]) = A4;
    __syncthreads();
    int d = tid;
    float A = (mrg[0][d] + mrg[1][d]) + (mrg[2][d] + mrg[3][d]);
    int h = ng * 4 + (r >> 4), pos = r & 15;
    attn[pos * 1024 + h * 128 + d] = A / Lsum;
}

// ---------- K4: out projection (pairwise) ----------
__global__ __launch_bounds__(256) void k_outproj(const float* __restrict__ W, // [768][1024]
                                                 const float* __restrict__ attn,
                                                 float* __restrict__ y) {
    int tid = threadIdx.x;
    int wv = tid >> 6, lane = tid & 63;
    int o0 = blockIdx.x * 8 + wv;
    int o1 = o0 + 4;
    float acca[TT], accb[TT];
    gemv_row2<256>(reinterpret_cast<const float4*>(W + (size_t)o0 * 1024),
                   reinterpret_cast<const float4*>(W + (size_t)o1 * 1024), attn, lane, acca, accb);
    if (lane < TT) {
        y[lane * DD + o0] = acca[lane];
        y[lane * DD + o1] = accb[lane];
    }
}

// ---------- K5: post-attn residual+norm, pre-ff norm, gate/up GEMV4 + GELU*up ----------
// grid 384, 8 f-rows/block.
__global__ __launch_bounds__(256) void k_gateup(const float* __restrict__ hA,
                                                const float* __restrict__ y,
                                                const float* __restrict__ postw,
                                                const float* __restrict__ pfn,
                                                const float* __restrict__ gw,
                                                const float* __restrict__ uw,
                                                float* __restrict__ act,
                                                float* __restrict__ hB) {
    __shared__ __align__(16) float xs[TT * DD];
    int tid = threadIdx.x;
    int row = tid >> 4, c16 = tid & 15;
    float4* xr = reinterpret_cast<float4*>(xs) + row * 192;
    const float4* y4 = reinterpret_cast<const float4*>(y) + row * 192;
    float ss = 0.f;
#pragma unroll
    for (int k = 0; k < 12; k++) { int i = c16 + 16 * k; float4 v = y4[i]; xr[i] = v; ss += d4(v, v); }
    ss = r16(ss);
    float inv = rsqrtf(ss * (1.f / 768.f) + EPSF);
    const float4* ha4 = reinterpret_cast<const float4*>(hA) + row * 192;
    const float4* pw4 = reinterpret_cast<const float4*>(postw);
    float4* hB4 = reinterpret_cast<float4*>(hB) + row * 192;
    float ss2 = 0.f;
#pragma unroll
    for (int k = 0; k < 12; k++) {
        int i = c16 + 16 * k;
        float4 v = f4res(ha4[i], xr[i], inv, pw4[i]);
        xr[i] = v; ss2 += d4(v, v);
        if (blockIdx.x == 0) hB4[i] = v;
    }
    ss2 = r16(ss2);
    float inv2 = rsqrtf(ss2 * (1.f / 768.f) + EPSF);
    const float4* pf4 = reinterpret_cast<const float4*>(pfn);
#pragma unroll
    for (int k = 0; k < 12; k++) { int i = c16 + 16 * k; xr[i] = f4nrm(xr[i], inv2, pf4[i]); }
    __syncthreads();
    int wv = tid >> 6, lane = tid & 63;
    int f0 = blockIdx.x * 8 + wv;
    int f1 = f0 + 4;
    float ag0[TT], ag1[TT], au0[TT], au1[TT];
    gemv_row4<192>(reinterpret_cast<const float4*>(gw + (size_t)f0 * DD),
                   reinterpret_cast<const float4*>(gw + (size_t)f1 * DD),
                   reinterpret_cast<const float4*>(uw + (size_t)f0 * DD),
                   reinterpret_cast<const float4*>(uw + (size_t)f1 * DD),
                   xs, lane, ag0, ag1, au0, au1);
    if (lane < TT) {
        {
            float g = ag0[lane], u = au0[lane];
            float inner = 0.7978845608028654f * fmaf(0.044715f * g, g * g, g);
            act[lane * FFF + f0] = 0.5f * g * (1.f + ftanh(inner)) * u;
        }
        {
            float g = ag1[lane], u = au1[lane];
            float inner = 0.7978845608028654f * fmaf(0.044715f * g, g * g, g);
            act[lane * FFF + f1] = 0.5f * g * (1.f + ftanh(inner)) * u;
        }
    }
}

// ---------- K6: down GEMV in f-quarters -> ff partials [4][16][768] ----------
// grid 384: fq = blk&3, dc = blk>>2 (0..95) x 8 rows (pairwise).
__global__ __launch_bounds__(256) void k_down(const float* __restrict__ W, // [768][3072]
                                              const float* __restrict__ act,
                                              float* __restrict__ ffp) {
    __shared__ __align__(16) float xs[TT * DD];
    int tid = threadIdx.x;
    int fq = blockIdx.x & 3, dc = blockIdx.x >> 2;
    {
        const float4* a4 = reinterpret_cast<const float4*>(act);
        float4* s4 = reinterpret_cast<float4*>(xs);
#pragma unroll
        for (int k = 0; k < 12; k++) {
            int i = tid + 256 * k;
            int t = i / 192, cq = i - t * 192;
            s4[i] = a4[t * 768 + fq * 192 + cq];
        }
    }
    __syncthreads();
    int wv = tid >> 6, lane = tid & 63;
    int o0 = dc * 8 + wv;
    int o1 = o0 + 4;
    float acca[TT], accb[TT];
    gemv_row2<192>(reinterpret_cast<const float4*>(W + (size_t)o0 * FFF + fq * 768),
                   reinterpret_cast<const float4*>(W + (size_t)o1 * FFF + fq * 768), xs, lane, acca, accb);
    if (lane < TT) {
        ffp[(fq * TT + lane) * DD + o0] = acca[lane];
        ffp[(fq * TT + lane) * DD + o1] = accb[lane];
    }
}

// ---------- lm_head with fused final-x (quad rows) ----------
// grid 500, 64 rows/block: 4 quads per wave.
__global__ __launch_bounds__(256) void k_lmfused(const float* __restrict__ hB,
                                                 const float* __restrict__ ff,    // [4][16][768]
                                                 const float* __restrict__ pofn25,
                                                 const float* __restrict__ fnw,
                                                 const float* __restrict__ W,     // [32000][768]
                                                 float* __restrict__ logits) {
    __shared__ __align__(16) float xs[TT * DD];
    int tid = threadIdx.x;
    int row = tid >> 4, c16 = tid & 15;
    float4* xr = reinterpret_cast<float4*>(xs) + row * 192;
    const float4* f0 = reinterpret_cast<const float4*>(ff) + row * 192;
    const float4* f1 = f0 + TT * 192;
    const float4* f2 = f1 + TT * 192;
    const float4* f3 = f2 + TT * 192;
    float ss = 0.f;
#pragma unroll
    for (int k = 0; k < 12; k++) {
        int i = c16 + 16 * k;
        float4 v = f4add4(f0[i], f1[i], f2[i], f3[i]);
        xr[i] = v; ss += d4(v, v);
    }
    ss = r16(ss);
    float inv = rsqrtf(ss * (1.f / 768.f) + EPSF);
    const float4* hb4 = reinterpret_cast<const float4*>(hB) + row * 192;
    const float4* po4 = reinterpret_cast<const float4*>(pofn25);
    float ss2 = 0.f;
#pragma unroll
    for (int k = 0; k < 12; k++) {
        int i = c16 + 16 * k;
        float4 v = f4res(hb4[i], xr[i], inv, po4[i]);
        xr[i] = v; ss2 += d4(v, v);
    }
    ss2 = r16(ss2);
    float inv2 = rsqrtf(ss2 * (1.f / 768.f) + EPSF);
    const float4* fn4 = reinterpret_cast<const float4*>(fnw);
#pragma unroll
    for (int k = 0; k < 12; k++) { int i = c16 + 16 * k; xr[i] = f4nrm(xr[i], inv2, fn4[i]); }
    __syncthreads();
    int wv = tid >> 6, lane = tid & 63;
#pragma unroll
    for (int rr = 0; rr < 4; ++rr) {
        int o0 = blockIdx.x * 64 + rr * 16 + wv;
        int o1 = o0 + 4;
        int o2 = o0 + 8;
        int o3 = o0 + 12;
        float acca[TT], accb[TT], accc[TT], accd[TT];
        gemv_row4<192>(reinterpret_cast<const float4*>(W + (size_t)o0 * DD),
                       reinterpret_cast<const float4*>(W + (size_t)o1 * DD),
                       reinterpret_cast<const float4*>(W + (size_t)o2 * DD),
                       reinterpret_cast<const float4*>(W + (size_t)o3 * DD),
                       xs, lane, acca, accb, accc, accd);
        if (lane < TT) {
            logits[lane * VV + o0] = acca[lane];
            logits[lane * VV + o1] = accb[lane];
            logits[lane * VV + o2] = accc[lane];
            logits[lane * VV + o3] = accd[lane];
        }
    }
}

extern "C" void kernel_launch(void* const* d_in, const int* in_sizes, int n_in,
                              void* d_out, int out_size, void* d_ws, size_t ws_size,
                              hipStream_t stream) {
    const float* emb   = (const float*)d_in[0];
    const float* maskg = (const float*)d_in[1];
    const float* maskl = (const float*)d_in[2];
    const float* cosg  = (const float*)d_in[3];
    const float* sing  = (const float*)d_in[4];
    const float* cosl  = (const float*)d_in[5];
    const float* sinl  = (const float*)d_in[6];
    const float* kck   = (const float*)d_in[7];
    const float* kcv   = (const float*)d_in[8];
    const float* pan   = (const float*)d_in[9];
    const float* qkvw  = (const float*)d_in[10];
    const float* qnw   = (const float*)d_in[11];
    const float* knw   = (const float*)d_in[12];
    const float* outw  = (const float*)d_in[13];
    const float* postw = (const float*)d_in[14];
    const float* pfnw  = (const float*)d_in[15];
    const float* gw    = (const float*)d_in[16];
    const float* uw    = (const float*)d_in[17];
    const float* dw    = (const float*)d_in[18];
    const float* pofn  = (const float*)d_in[19];
    const float* fnw   = (const float*)d_in[20];
    const float* lmw   = (const float*)d_in[21];

    float* ws   = (float*)d_ws;
    float* hA   = ws;                 // 12288
    float* hB   = hA + 12288;         // 12288
    float* qkvb = hB + 12288;         // 24576
    float* attnb = qkvb + 24576;      // 16384
    float* yb   = attnb + 16384;      // 12288
    float* act  = yb + 12288;         // 49152
    float* ffp  = act + 49152;        // 49152
    float* part = ffp + 49152;        // 2*65*64*132 = 1,098,240

    float* outp = (float*)d_out;
    float* outK = outp + 512000;
    float* outV = outK + 106496;

    for (int l = 0; l < NL; l++) {
        int loc = ((l + 1) % 6) == 0;
        const float* cosp = loc ? cosl : cosg;
        const float* sinp = loc ? sinl : sing;
        const float* maskp = loc ? maskl : maskg;
        k_qkv<<<192, 256, 0, stream>>>(l == 0 ? 1 : 0, hB, ffp, emb,
                                       l ? (pofn + (size_t)(l - 1) * DD) : pofn,
                                       pan + (size_t)l * DD,
                                       qkvw + (size_t)l * OQKV * DD, qkvb, hA);
        k_attn<<<dim3(NCH, 2, 4), 256, 0, stream>>>(qkvb,
                                                    kck + (size_t)l * 2 * SCCH * HDD,
                                                    kcv + (size_t)l * 2 * HDD * SCCH,
                                                    cosp, sinp, maskp,
                                                    qnw + (size_t)l * HDD, knw + (size_t)l * HDD,
                                                    part,
                                                    outK + (size_t)l * 2 * TT * HDD,
                                                    outV + (size_t)l * 2 * HDD * TT);
        k_combine<<<128, 128, 0, stream>>>(part, attnb);
        k_outproj<<<96, 256, 0, stream>>>(outw + (size_t)l * DD * 1024, attnb, yb);
        k_gateup<<<384, 256, 0, stream>>>(hA, yb, postw + (size_t)l * DD, pfnw + (size_t)l * DD,
                                          gw + (size_t)l * FFF * DD, uw + (size_t)l * FFF * DD,
                                          act, hB);
        k_down<<<384, 256, 0, stream>>>(dw + (size_t)l * DD * FFF, act, ffp);
    }
    k_lmfused<<<500, 256, 0, stream>>>(hB, ffp, pofn + (size_t)25 * DD, fnw, lmw, outp);
}